// Round 3
// baseline (10659.167 us; speedup 1.0000x reference)
//
#include <hip/hip_runtime.h>
#include <math.h>

#define N_SEQ 4096
#define KCH   16
#define DM    256
#define G4    1024
#define BM    128
#define BN    64
#define BK    16

__device__ __forceinline__ float sigf(float x) { return 1.f / (1.f + __expf(-x)); }
__device__ __forceinline__ float bf2f(unsigned short u) {
    return __uint_as_float(((unsigned)u) << 16);
}
__device__ __forceinline__ unsigned short f2bf(float f) {
    unsigned u = __float_as_uint(f);
    unsigned r = (u + 0x7fffu + ((u >> 16) & 1u)) >> 16;   // RNE
    return (unsigned short)r;
}
__device__ __forceinline__ float4 ldA4(const float* p) { return *(const float4*)p; }
__device__ __forceinline__ float4 ldA4(const unsigned short* p) {
    ushort4 u = *(const ushort4*)p;  // 8B-aligned
    return make_float4(bf2f(u.x), bf2f(u.y), bf2f(u.z), bf2f(u.w));
}

// ---------------------------------------------------------------------------
// acc[8][4] += A(128 rows, K=256) @ B(64 rows, K=256)^T
// AMODE: 0 = direct rows, 1 = gather via idxarr[row*KCH + kk_idx] (clamped),
//        2 = gather via idxarr[row].  B pre-offset to the 64-row col-tile.
// ---------------------------------------------------------------------------
template<int AMODE, typename TA>
__device__ __forceinline__ void gemm_pass(
    const TA* __restrict__ A, int lda,
    const int* __restrict__ idxarr, int kk_idx,
    const float* __restrict__ B, int ldb,
    float (&acc)[8][4],
    float (*As)[BM + 4], float (*Bs)[BN + 4],
    int row0)
{
    const int tid  = threadIdx.x;
    const int lrow = tid >> 2;   // 0..63
    const int q    = tid & 3;    // k-quad
    const int ty   = tid >> 4;   // 0..15
    const int tx   = tid & 15;   // 0..15

    const TA* arow0; const TA* arow1;
    {
        const int r0 = row0 + lrow, r1 = r0 + 64;
        if (AMODE == 0) {
            arow0 = A + (size_t)r0 * lda;
            arow1 = A + (size_t)r1 * lda;
        } else if (AMODE == 1) {
            int i0 = idxarr[r0 * KCH + kk_idx]; if (i0 < 0) i0 = 0;
            int i1 = idxarr[r1 * KCH + kk_idx]; if (i1 < 0) i1 = 0;
            arow0 = A + (size_t)i0 * lda;
            arow1 = A + (size_t)i1 * lda;
        } else {
            arow0 = A + (size_t)idxarr[r0] * lda;
            arow1 = A + (size_t)idxarr[r1] * lda;
        }
    }
    const float* brow = B + (size_t)lrow * ldb;

    for (int k0 = 0; k0 < DM; k0 += BK) {
        __syncthreads();
        float4 v = ldA4(arow0 + k0 + q * 4);
        As[q*4+0][lrow] = v.x; As[q*4+1][lrow] = v.y;
        As[q*4+2][lrow] = v.z; As[q*4+3][lrow] = v.w;
        v = ldA4(arow1 + k0 + q * 4);
        As[q*4+0][lrow+64] = v.x; As[q*4+1][lrow+64] = v.y;
        As[q*4+2][lrow+64] = v.z; As[q*4+3][lrow+64] = v.w;
        float4 w = *(const float4*)(brow + k0 + q * 4);
        Bs[q*4+0][lrow] = w.x; Bs[q*4+1][lrow] = w.y;
        Bs[q*4+2][lrow] = w.z; Bs[q*4+3][lrow] = w.w;
        __syncthreads();
#pragma unroll
        for (int kk = 0; kk < BK; ++kk) {
            float a[8], b[4];
            *(float4*)&a[0] = *(const float4*)&As[kk][ty * 8];
            *(float4*)&a[4] = *(const float4*)&As[kk][ty * 8 + 4];
            *(float4*)&b[0] = *(const float4*)&Bs[kk][tx * 4];
#pragma unroll
            for (int i = 0; i < 8; ++i)
#pragma unroll
                for (int j = 0; j < 4; ++j)
                    acc[i][j] = fmaf(a[i], b[j], acc[i][j]);
        }
    }
}

// --------------------------- small setup kernels ----------------------------

__global__ __launch_bounds__(256) void k_lastidx(
    const int* __restrict__ indice, int* __restrict__ last_idx)
{
    const int n = blockIdx.x * 256 + threadIdx.x;
    if (n >= N_SEQ) return;
    int len = 0;
#pragma unroll
    for (int k = 0; k < KCH; ++k) len += (indice[n * KCH + k] != -1);
    last_idx[n] = indice[n * KCH + (len - 1)];
}

__global__ __launch_bounds__(1024) void k_bsum_hh0(
    const float* __restrict__ bih, const float* __restrict__ bhh,
    const float* __restrict__ h0, const float* __restrict__ Whh,
    float* __restrict__ bsum, float* __restrict__ hh0)
{
    const int jd = blockIdx.x, g = threadIdx.x;   // jd in [0,8), g in [0,1024)
    float b = bih[jd * G4 + g] + bhh[jd * G4 + g];
    bsum[jd * G4 + g] = b;
    if (jd & 1) {
        const int j = jd >> 1;
        const float* wrow = Whh + ((size_t)jd * G4 + g) * DM;
        float s = b;
        for (int h = 0; h < DM; ++h) s = fmaf(h0[j * DM + h], wrow[h], s);
        hh0[j * G4 + g] = s;
    }
}

// h_bufA (bf16) and c_state (fp32) <- broadcast initial state per scan s
__global__ __launch_bounds__(256) void k_init_states(
    const float* __restrict__ h0, const float* __restrict__ c0,
    unsigned short* __restrict__ hA, float* __restrict__ c_state)
{
    const int row = blockIdx.x;             // 0 .. 5*N_SEQ-1
    const int s = row >> 12;                // N_SEQ = 4096
    const int tree = (s < 4) ? s : 0;
    const int d = threadIdx.x;
    hA[(size_t)row * DM + d]      = f2bf(h0[tree * DM + d]);
    c_state[(size_t)row * DM + d] = c0[tree * DM + d];
}

__global__ __launch_bounds__(256) void k_zero4(float4* __restrict__ p)
{
    p[(size_t)blockIdx.x * 256 + threadIdx.x] = make_float4(0.f, 0.f, 0.f, 0.f);
}

// --------------------------- fused scan round -------------------------------
// grid (4, 32, 5). Per block: rows [bm*128,+128), d-cols [bn*64,+64), all 4
// gates (order u,i,f,o) with a bf16 LDS stash. Reads h_in, writes h_out
// (ping-pong), updates c_state in place (cell owned by exactly this block).
__global__ __launch_bounds__(256) void k_scan_fused(
    const float* __restrict__ h_tensor, const int* __restrict__ indice,
    const unsigned short* __restrict__ h_in, unsigned short* __restrict__ h_out,
    float* __restrict__ c_state,
    const float* __restrict__ Wih, const float* __restrict__ Whh,
    const float* __restrict__ bsum,
    unsigned short* __restrict__ y_cur,   // [2][N][256]: 0=fwd tree0, 1=bwd tree0
    int r)
{
    __shared__ float As[BK][BM + 4];
    __shared__ float Bs[BK][BN + 4];
    __shared__ unsigned short stash[BM][BN];

    const int bn = blockIdx.x;            // 0..3
    const int bm = blockIdx.y;            // 0..31
    const int s  = blockIdx.z;            // 0..4
    const int k  = (s < 4) ? r : (KCH - 1 - r);
    const int wsel = (s < 4) ? s * 2 : 1;
    const int tid = threadIdx.x;
    const int ty = tid >> 4, tx = tid & 15;
    const int row0 = bm * BM;
    const int colbase = bn * BN;          // d-range base, 0..192

    int mrow[8];
#pragma unroll
    for (int i = 0; i < 8; ++i)
        mrow[i] = indice[(row0 + ty * 8 + i) * KCH + k];

    const unsigned short* hs_in = h_in + (size_t)s * N_SEQ * DM;
    const int gate_order[4] = {2, 0, 1, 3};   // u, i, f, o

#pragma unroll
    for (int gg = 0; gg < 4; ++gg) {
        const int gi = gate_order[gg];
        const int gcol = gi * DM + colbase;     // gate-dim col base in [0,1024)
        float acc[8][4];
#pragma unroll
        for (int i = 0; i < 8; ++i)
#pragma unroll
            for (int j = 0; j < 4; ++j) acc[i][j] = 0.f;

        gemm_pass<1, float>(h_tensor, DM, indice, k,
                            Wih + ((size_t)wsel * G4 + gcol) * DM, DM,
                            acc, As, Bs, row0);
        gemm_pass<0, unsigned short>(hs_in, DM, nullptr, 0,
                            Whh + ((size_t)wsel * G4 + gcol) * DM, DM,
                            acc, As, Bs, row0);

        const float* bptr = bsum + (size_t)wsel * G4 + gcol + tx * 4;
#pragma unroll
        for (int i = 0; i < 8; ++i) {
            const int rr = ty * 8 + i;
            const int grow = row0 + rr;
            const bool m = (mrow[i] != -1);
#pragma unroll
            for (int j = 0; j < 4; ++j) {
                const int cc = tx * 4 + j;
                const int d  = colbase + cc;
                const float gval = acc[i][j] + bptr[j];
                if (gg == 0) {                     // u = tanh
                    stash[rr][cc] = f2bf(tanhf(gval));
                } else if (gg == 1) {              // i: stash = i*u
                    stash[rr][cc] = f2bf(sigf(gval) * bf2f(stash[rr][cc]));
                } else if (gg == 2) {              // f: c_new = f*c_old + i*u
                    const size_t cix = ((size_t)s * N_SEQ + grow) * DM + d;
                    const float c_old = c_state[cix];
                    const float c_new = sigf(gval) * c_old + bf2f(stash[rr][cc]);
                    const float c_wr = m ? c_new : c_old;
                    c_state[cix] = c_wr;
                    stash[rr][cc] = f2bf(tanhf(c_wr));
                } else {                           // o: h_new = o*tanh(c)
                    const float hn = sigf(gval) * bf2f(stash[rr][cc]);
                    const size_t hix = ((size_t)s * N_SEQ + grow) * DM + d;
                    const unsigned short hv = m ? f2bf(hn) : h_in[hix];
                    h_out[hix] = hv;
                    if (s == 0)
                        y_cur[(size_t)grow * DM + d] = m ? f2bf(hn) : (unsigned short)0;
                    if (s == 4)
                        y_cur[(size_t)(N_SEQ + grow) * DM + d] = m ? f2bf(hn) : (unsigned short)0;
                }
            }
        }
    }
}

// ys0[n, kslice, :] += y_cur[z] @ fc0(half z)^T     grid (4, 32, 2)
__global__ __launch_bounds__(256) void k_acc_fc(
    const unsigned short* __restrict__ y_cur, const float* __restrict__ fc,
    unsigned short* __restrict__ ys0, int r)
{
    __shared__ float As[BK][BM + 4];
    __shared__ float Bs[BK][BN + 4];
    const int z = blockIdx.z;
    const int kslice = (z == 0) ? r : (KCH - 1 - r);
    const int row0 = blockIdx.y * BM;
    const int colbase = blockIdx.x * BN;
    const int ty = threadIdx.x >> 4, tx = threadIdx.x & 15;

    float acc[8][4];
#pragma unroll
    for (int i = 0; i < 8; ++i)
#pragma unroll
        for (int j = 0; j < 4; ++j) acc[i][j] = 0.f;

    gemm_pass<0, unsigned short>(y_cur + (size_t)z * N_SEQ * DM, DM, nullptr, 0,
                                 fc + (size_t)colbase * (2 * DM) + z * DM, 2 * DM,
                                 acc, As, Bs, row0);
#pragma unroll
    for (int i = 0; i < 8; ++i) {
        const int grow = row0 + ty * 8 + i;
        unsigned short* crow = ys0 + ((size_t)grow * KCH + kslice) * DM + colbase + tx * 4;
#pragma unroll
        for (int j = 0; j < 4; ++j)
            crow[j] = f2bf(bf2f(crow[j]) + acc[i][j]);
    }
}

// Wx = x @ W_w^T + W_b  (bf16 out)   grid (16, 32)
__global__ __launch_bounds__(256) void k_wx(
    const float* __restrict__ x, const float* __restrict__ W_w,
    const float* __restrict__ W_b, unsigned short* __restrict__ Wx)
{
    __shared__ float As[BK][BM + 4];
    __shared__ float Bs[BK][BN + 4];
    const int row0 = blockIdx.y * BM;
    const int colbase = blockIdx.x * BN;     // 0..960
    const int ty = threadIdx.x >> 4, tx = threadIdx.x & 15;

    float acc[8][4];
#pragma unroll
    for (int i = 0; i < 8; ++i)
#pragma unroll
        for (int j = 0; j < 4; ++j) acc[i][j] = 0.f;

    gemm_pass<0, float>(x, DM, nullptr, 0,
                        W_w + (size_t)colbase * DM, DM,
                        acc, As, Bs, row0);
#pragma unroll
    for (int i = 0; i < 8; ++i) {
        const int grow = row0 + ty * 8 + i;
#pragma unroll
        for (int j = 0; j < 4; ++j) {
            const int col = colbase + tx * 4 + j;
            Wx[(size_t)grow * G4 + col] = f2bf(acc[i][j] + W_b[col]);
        }
    }
}

// Backward single step for trees 1..3 (carry still initial at k=last):
// gates = h_tensor[last_idx] @ Wih[j,1]^T + hh0[j]; yb = o*tanh(f*c0 + i*u)
__global__ __launch_bounds__(256) void k_bwd_fused(
    const float* __restrict__ h_tensor, const int* __restrict__ last_idx,
    const float* __restrict__ Wih, const float* __restrict__ hh0,
    const float* __restrict__ c0, unsigned short* __restrict__ yb_last)
{
    __shared__ float As[BK][BM + 4];
    __shared__ float Bs[BK][BN + 4];
    __shared__ unsigned short stash[BM][BN];
    const int jz = blockIdx.z, j = jz + 1, wsel = j * 2 + 1;
    const int row0 = blockIdx.y * BM;
    const int colbase = blockIdx.x * BN;
    const int ty = threadIdx.x >> 4, tx = threadIdx.x & 15;
    const int gate_order[4] = {2, 0, 1, 3};

#pragma unroll
    for (int gg = 0; gg < 4; ++gg) {
        const int gi = gate_order[gg];
        const int gcol = gi * DM + colbase;
        float acc[8][4];
#pragma unroll
        for (int i = 0; i < 8; ++i)
#pragma unroll
            for (int j2 = 0; j2 < 4; ++j2) acc[i][j2] = 0.f;

        gemm_pass<2, float>(h_tensor, DM, last_idx, 0,
                            Wih + ((size_t)wsel * G4 + gcol) * DM, DM,
                            acc, As, Bs, row0);

        const float* bptr = hh0 + (size_t)j * G4 + gcol + tx * 4;
#pragma unroll
        for (int i = 0; i < 8; ++i) {
            const int rr = ty * 8 + i;
            const int grow = row0 + rr;
#pragma unroll
            for (int j2 = 0; j2 < 4; ++j2) {
                const int cc = tx * 4 + j2;
                const int d  = colbase + cc;
                const float gval = acc[i][j2] + bptr[j2];
                if (gg == 0) {
                    stash[rr][cc] = f2bf(tanhf(gval));
                } else if (gg == 1) {
                    stash[rr][cc] = f2bf(sigf(gval) * bf2f(stash[rr][cc]));
                } else if (gg == 2) {
                    const float c_new = sigf(gval) * c0[j * DM + d] + bf2f(stash[rr][cc]);
                    stash[rr][cc] = f2bf(tanhf(c_new));
                } else {
                    const float hn = sigf(gval) * bf2f(stash[rr][cc]);
                    yb_last[((size_t)jz * N_SEQ + grow) * DM + d] = f2bf(hn);
                }
            }
        }
    }
}

// ys_last[jz] = h_final[1+jz] @ fcj[:, :256]^T + yb_last[jz] @ fcj[:, 256:]^T
__global__ __launch_bounds__(256) void k_fc_last(
    const unsigned short* __restrict__ h_final, const unsigned short* __restrict__ yb_last,
    const float* __restrict__ fc, unsigned short* __restrict__ ys_last)
{
    __shared__ float As[BK][BM + 4];
    __shared__ float Bs[BK][BN + 4];
    const int jz = blockIdx.z, j = jz + 1;
    const float* fcj = fc + (size_t)j * DM * (2 * DM);
    const int row0 = blockIdx.y * BM;
    const int colbase = blockIdx.x * BN;
    const int ty = threadIdx.x >> 4, tx = threadIdx.x & 15;

    float acc[8][4];
#pragma unroll
    for (int i = 0; i < 8; ++i)
#pragma unroll
        for (int j2 = 0; j2 < 4; ++j2) acc[i][j2] = 0.f;

    gemm_pass<0, unsigned short>(h_final + (size_t)(1 + jz) * N_SEQ * DM, DM, nullptr, 0,
                                 fcj + (size_t)colbase * (2 * DM), 2 * DM,
                                 acc, As, Bs, row0);
    gemm_pass<0, unsigned short>(yb_last + (size_t)jz * N_SEQ * DM, DM, nullptr, 0,
                                 fcj + (size_t)colbase * (2 * DM) + DM, 2 * DM,
                                 acc, As, Bs, row0);
#pragma unroll
    for (int i = 0; i < 8; ++i) {
        const int grow = row0 + ty * 8 + i;
#pragma unroll
        for (int j2 = 0; j2 < 4; ++j2)
            ys_last[((size_t)jz * N_SEQ + grow) * DM + colbase + tx * 4 + j2] = f2bf(acc[i][j2]);
    }
}

// Final combine -> (new_h, new_c)
__global__ __launch_bounds__(256) void k_final(
    const unsigned short* __restrict__ Wx, const unsigned short* __restrict__ ys0,
    const unsigned short* __restrict__ ys_last, const float* __restrict__ c_tensor,
    const int* __restrict__ indice, float* __restrict__ out)
{
    const int n = blockIdx.x, d = threadIdx.x;
    const float Wf = bf2f(Wx[(size_t)n * G4 + d]);
    const float Wi = bf2f(Wx[(size_t)n * G4 + DM + d]);
    const float Wu = bf2f(Wx[(size_t)n * G4 + 2 * DM + d]);
    const float Wo = bf2f(Wx[(size_t)n * G4 + 3 * DM + d]);
    float bf = 0.f;
#pragma unroll
    for (int k = 0; k < KCH; ++k) {
        const int id = indice[n * KCH + k];
        if (id >= 0)
            bf += sigf(Wf + bf2f(ys0[((size_t)n * KCH + k) * DM + d])) *
                  c_tensor[(size_t)id * DM + d];
    }
    const float bi = sigf(bf2f(ys_last[((size_t)0 * N_SEQ + n) * DM + d]) + Wi);
    const float bu = tanhf(bf2f(ys_last[((size_t)1 * N_SEQ + n) * DM + d]) + Wu);
    const float bo = sigf(bf2f(ys_last[((size_t)2 * N_SEQ + n) * DM + d]) + Wo);
    const float nc = bi * bu + bf;
    const float nh = bo * tanhf(nc);
    out[(size_t)n * DM + d] = nh;
    out[(size_t)N_SEQ * DM + (size_t)n * DM + d] = nc;
}

// --------------------------- launcher ---------------------------------------
extern "C" void kernel_launch(void* const* d_in, const int* in_sizes, int n_in,
                              void* d_out, int out_size, void* d_ws, size_t ws_size,
                              hipStream_t stream)
{
    const float* x        = (const float*)d_in[0];
    const float* h_tensor = (const float*)d_in[1];
    const float* c_tensor = (const float*)d_in[2];
    const int*   indice   = (const int*)d_in[3];
    const float* W_w      = (const float*)d_in[4];
    const float* W_b      = (const float*)d_in[5];
    const float* h0       = (const float*)d_in[6];
    const float* c0       = (const float*)d_in[7];
    const float* Wih      = (const float*)d_in[8];
    const float* Whh      = (const float*)d_in[9];
    const float* bih      = (const float*)d_in[10];
    const float* bhh      = (const float*)d_in[11];
    const float* fc       = (const float*)d_in[12];
    float* out = (float*)d_out;

    // byte offsets (all 16B-aligned)
    char* base = (char*)d_ws;
    float*          c_state  = (float*)(base + 0);              // 20,971,520
    float*          bsum     = (float*)(base + 20971520);       //     32,768
    float*          hh0      = (float*)(base + 21004288);       //     16,384
    int*            last_idx = (int*)  (base + 21020672);       //     16,384
    unsigned short* hA       = (unsigned short*)(base + 21037056);  // 10,485,760
    unsigned short* hB       = (unsigned short*)(base + 31522816);  // 10,485,760
    unsigned short* y_cur    = (unsigned short*)(base + 42008576);  //  4,194,304
    unsigned short* ys0      = (unsigned short*)(base + 46202880);  // 33,554,432
    unsigned short* Wx       = (unsigned short*)(base + 79757312);  //  8,388,608
    unsigned short* yb_last  = (unsigned short*)(base + 88145920);  //  6,291,456
    unsigned short* ys_last  = (unsigned short*)(base + 94437376);  //  6,291,456
    const size_t need = 100728832;
    if (ws_size < need) return;   // diagnostic: zero-output absmax fail, no crash

    k_lastidx<<<16, 256, 0, stream>>>(indice, last_idx);
    k_bsum_hh0<<<8, 1024, 0, stream>>>(bih, bhh, h0, Whh, bsum, hh0);
    k_init_states<<<5 * N_SEQ, 256, 0, stream>>>(h0, c0, hA, c_state);
    k_zero4<<<8192, 256, 0, stream>>>((float4*)ys0);   // 32 MB of zeros
    k_wx<<<dim3(16, 32), 256, 0, stream>>>(x, W_w, W_b, Wx);

    for (int r = 0; r < KCH; ++r) {
        const unsigned short* h_in = (r & 1) ? hB : hA;
        unsigned short* h_out      = (r & 1) ? hA : hB;
        k_scan_fused<<<dim3(4, 32, 5), 256, 0, stream>>>(
            h_tensor, indice, h_in, h_out, c_state, Wih, Whh, bsum, y_cur, r);
        k_acc_fc<<<dim3(4, 32, 2), 256, 0, stream>>>(y_cur, fc, ys0, r);
    }
    // after r=15 (odd), final h is in hA

    k_bwd_fused<<<dim3(4, 32, 3), 256, 0, stream>>>(
        h_tensor, last_idx, Wih, hh0, c0, yb_last);
    k_fc_last<<<dim3(4, 32, 3), 256, 0, stream>>>(hA, yb_last, fc, ys_last);

    k_final<<<N_SEQ, 256, 0, stream>>>(Wx, ys0, ys_last, c_tensor, indice, out);
}

// Round 4
// 2010.305 us; speedup vs baseline: 5.3023x; 5.3023x over previous
//
#include <hip/hip_runtime.h>
#include <math.h>

#define N_SEQ 4096
#define KCH   16
#define DM    256
#define G4    1024
// fp32 fallback GEMM tile (one-shot kernels)
#define BM    128
#define BN    64
#define BK    16
// MFMA LDS pitch: 32 k bf16 (64B) + 16B pad = 80B = 40 ushorts
#define LP    40
#define EP    68   // epilogue scratch pitch in floats

typedef __attribute__((ext_vector_type(8))) short bf8;
typedef __attribute__((ext_vector_type(4))) float f4;

__device__ __forceinline__ float sigf(float x) { return 1.f / (1.f + __expf(-x)); }
__device__ __forceinline__ float bf2f(unsigned short u) {
    return __uint_as_float(((unsigned)u) << 16);
}
__device__ __forceinline__ unsigned short f2bf(float f) {
    unsigned u = __float_as_uint(f);
    unsigned r = (u + 0x7fffu + ((u >> 16) & 1u)) >> 16;   // RNE
    return (unsigned short)r;
}
__device__ __forceinline__ unsigned pack2(float a, float b) {
    return (unsigned)f2bf(a) | ((unsigned)f2bf(b) << 16);
}
__device__ __forceinline__ float4 ldA4(const float* p) { return *(const float4*)p; }
__device__ __forceinline__ float4 ldA4(const unsigned short* p) {
    ushort4 u = *(const ushort4*)p;
    return make_float4(bf2f(u.x), bf2f(u.y), bf2f(u.z), bf2f(u.w));
}

// ===========================================================================
// MFMA core: acc[4][4] (f32x4 each) += A[128,KTOT] @ B[128,KTOT]^T (bf16)
// A k<KX from fp32 row aX (converted), k>=KX from bf16 row aH (indexed k-KX).
// 256 thr = 4 waves (2x2 of 64x64). Staging: thread t handles row t>>1,
// k-half (t&1)*16. LDS rows padded to 80B.
// ===========================================================================
template<int KTOT, int KX>
__device__ __forceinline__ void mfma_gemm(
    const float* __restrict__ aX, const unsigned short* __restrict__ aH,
    const unsigned short* __restrict__ bR,
    unsigned short* Asm, unsigned short* Bsm, f4 (&acc)[4][4])
{
    const int tid  = threadIdx.x;
    const int srow = tid >> 1;
    const int kh   = (tid & 1) * 16;
    const int lane = tid & 63;
    const int wave = tid >> 6;
    const int wm   = (wave >> 1) * 64;
    const int wn   = (wave & 1) * 64;
    const int fr   = lane & 15;
    const int fk   = (lane >> 4) * 8;

    unsigned short* da = Asm + srow * LP + kh;
    unsigned short* db = Bsm + srow * LP + kh;

    for (int k0 = 0; k0 < KTOT; k0 += 32) {
        __syncthreads();
        if (KX > 0 && k0 < KX) {
            const float* s = aX + k0 + kh;
            float4 v0 = *(const float4*)(s);
            float4 v1 = *(const float4*)(s + 4);
            float4 v2 = *(const float4*)(s + 8);
            float4 v3 = *(const float4*)(s + 12);
            int4 w0 = make_int4(pack2(v0.x, v0.y), pack2(v0.z, v0.w),
                                pack2(v1.x, v1.y), pack2(v1.z, v1.w));
            int4 w1 = make_int4(pack2(v2.x, v2.y), pack2(v2.z, v2.w),
                                pack2(v3.x, v3.y), pack2(v3.z, v3.w));
            *(int4*)(da)     = w0;
            *(int4*)(da + 8) = w1;
        } else {
            const unsigned short* s = aH + (k0 - KX) + kh;
            *(int4*)(da)     = *(const int4*)(s);
            *(int4*)(da + 8) = *(const int4*)(s + 8);
        }
        {
            const unsigned short* s = bR + k0 + kh;
            *(int4*)(db)     = *(const int4*)(s);
            *(int4*)(db + 8) = *(const int4*)(s + 8);
        }
        __syncthreads();

        bf8 af[4], bfr[4];
#pragma unroll
        for (int i = 0; i < 4; ++i)
            af[i] = *(const bf8*)(Asm + (wm + i * 16 + fr) * LP + fk);
#pragma unroll
        for (int j = 0; j < 4; ++j)
            bfr[j] = *(const bf8*)(Bsm + (wn + j * 16 + fr) * LP + fk);
#pragma unroll
        for (int i = 0; i < 4; ++i)
#pragma unroll
            for (int j = 0; j < 4; ++j)
                acc[i][j] = __builtin_amdgcn_mfma_f32_16x16x32_bf16(
                    af[i], bfr[j], acc[i][j], 0, 0, 0);
    }
}

// ===========================================================================
// fp32 fallback core (one-shot kernels, proven in round 3)
// ===========================================================================
template<int AMODE, typename TA>
__device__ __forceinline__ void gemm_pass(
    const TA* __restrict__ A, int lda,
    const int* __restrict__ idxarr, int kk_idx,
    const float* __restrict__ B, int ldb,
    float (&acc)[8][4],
    float (*As)[BM + 4], float (*Bs)[BN + 4],
    int row0)
{
    const int tid  = threadIdx.x;
    const int lrow = tid >> 2;
    const int q    = tid & 3;
    const int ty   = tid >> 4;
    const int tx   = tid & 15;

    const TA* arow0; const TA* arow1;
    {
        const int r0 = row0 + lrow, r1 = r0 + 64;
        if (AMODE == 0) {
            arow0 = A + (size_t)r0 * lda;
            arow1 = A + (size_t)r1 * lda;
        } else if (AMODE == 1) {
            int i0 = idxarr[r0 * KCH + kk_idx]; if (i0 < 0) i0 = 0;
            int i1 = idxarr[r1 * KCH + kk_idx]; if (i1 < 0) i1 = 0;
            arow0 = A + (size_t)i0 * lda;
            arow1 = A + (size_t)i1 * lda;
        } else {
            arow0 = A + (size_t)idxarr[r0] * lda;
            arow1 = A + (size_t)idxarr[r1] * lda;
        }
    }
    const float* brow = B + (size_t)lrow * ldb;

    for (int k0 = 0; k0 < DM; k0 += BK) {
        __syncthreads();
        float4 v = ldA4(arow0 + k0 + q * 4);
        As[q*4+0][lrow] = v.x; As[q*4+1][lrow] = v.y;
        As[q*4+2][lrow] = v.z; As[q*4+3][lrow] = v.w;
        v = ldA4(arow1 + k0 + q * 4);
        As[q*4+0][lrow+64] = v.x; As[q*4+1][lrow+64] = v.y;
        As[q*4+2][lrow+64] = v.z; As[q*4+3][lrow+64] = v.w;
        float4 w = *(const float4*)(brow + k0 + q * 4);
        Bs[q*4+0][lrow] = w.x; Bs[q*4+1][lrow] = w.y;
        Bs[q*4+2][lrow] = w.z; Bs[q*4+3][lrow] = w.w;
        __syncthreads();
#pragma unroll
        for (int kk = 0; kk < BK; ++kk) {
            float a[8], b[4];
            *(float4*)&a[0] = *(const float4*)&As[kk][ty * 8];
            *(float4*)&a[4] = *(const float4*)&As[kk][ty * 8 + 4];
            *(float4*)&b[0] = *(const float4*)&Bs[kk][tx * 4];
#pragma unroll
            for (int i = 0; i < 8; ++i)
#pragma unroll
                for (int j = 0; j < 4; ++j)
                    acc[i][j] = fmaf(a[i], b[j], acc[i][j]);
        }
    }
}

// --------------------------- setup kernels ----------------------------------

__global__ __launch_bounds__(256) void k_lastidx(
    const int* __restrict__ indice, int* __restrict__ last_idx)
{
    const int n = blockIdx.x * 256 + threadIdx.x;
    if (n >= N_SEQ) return;
    int len = 0;
#pragma unroll
    for (int k = 0; k < KCH; ++k) len += (indice[n * KCH + k] != -1);
    last_idx[n] = indice[n * KCH + (len - 1)];
}

__global__ __launch_bounds__(1024) void k_hh0(
    const float* __restrict__ bih, const float* __restrict__ bhh,
    const float* __restrict__ h0, const float* __restrict__ Whh,
    float* __restrict__ hh0)
{
    const int j = blockIdx.x + 1;           // trees 1..3
    const int g = threadIdx.x;
    const int jd = j * 2 + 1;
    const float* wrow = Whh + ((size_t)jd * G4 + g) * DM;
    float s = bih[jd * G4 + g] + bhh[jd * G4 + g];
    for (int h = 0; h < DM; ++h) s = fmaf(h0[j * DM + h], wrow[h], s);
    hh0[j * G4 + g] = s;
}

__global__ __launch_bounds__(256) void k_init_states(
    const float* __restrict__ h0, const float* __restrict__ c0,
    unsigned short* __restrict__ hA, float* __restrict__ c_state)
{
    const int row = blockIdx.x;             // 0 .. 5*N_SEQ-1
    const int s = row >> 12;
    const int tree = (s < 4) ? s : 0;
    const int d = threadIdx.x;
    hA[(size_t)row * DM + d]      = f2bf(h0[tree * DM + d]);
    c_state[(size_t)row * DM + d] = c0[tree * DM + d];
}

__global__ __launch_bounds__(256) void k_zero4(float4* __restrict__ p)
{
    p[(size_t)blockIdx.x * 256 + threadIdx.x] = make_float4(0.f, 0.f, 0.f, 0.f);
}

// Wcat[s][c=d*4+g][0:256]=Wih row(g*256+d); [256:512]=Whh row. + bsumr.
__global__ __launch_bounds__(256) void k_prep_wcat(
    const float* __restrict__ Wih, const float* __restrict__ Whh,
    const float* __restrict__ bih, const float* __restrict__ bhh,
    unsigned short* __restrict__ wcat, float* __restrict__ bsumr)
{
    const int c = blockIdx.x;              // 0..1023
    const int s = blockIdx.y;              // 0..4
    const int wsel = (s < 4) ? s * 2 : 1;
    const int d = c >> 2, g = c & 3;
    const size_t srcrow = ((size_t)wsel * G4 + g * DM + d) * DM;
    unsigned short* dst = wcat + ((size_t)s * G4 + c) * 512;
    const int t = threadIdx.x;
    dst[t]       = f2bf(Wih[srcrow + t]);
    dst[256 + t] = f2bf(Whh[srcrow + t]);
    if (t == 0)
        bsumr[s * G4 + c] = bih[wsel * G4 + g * DM + d] + bhh[wsel * G4 + g * DM + d];
}

// fcb[z][dout][k] = fc[0][dout][z*256+k]  (bf16)
__global__ __launch_bounds__(256) void k_prep_fcb(
    const float* __restrict__ fc, unsigned short* __restrict__ fcb)
{
    const int dout = blockIdx.x, z = blockIdx.y, t = threadIdx.x;
    fcb[((size_t)z * DM + dout) * DM + t] = f2bf(fc[(size_t)dout * 512 + z * DM + t]);
}

// --------------------------- MFMA scan round --------------------------------
// grid (8, 32, 5). Block: rows [bm*128), interleaved gate-cols [bn*128) =
// 32 d-values x 4 gates. Fused LSTM epilogue via per-wave LDS transpose.
__global__ __launch_bounds__(256) void k_scan_mfma(
    const float* __restrict__ h_tensor, const int* __restrict__ indice,
    const unsigned short* __restrict__ h_in, unsigned short* __restrict__ h_out,
    float* __restrict__ c_state,
    const unsigned short* __restrict__ wcat, const float* __restrict__ bsumr,
    unsigned short* __restrict__ y_cur, int r)
{
    __shared__ __align__(16) unsigned short SMEM[2 * 128 * LP];  // 20480 B
    unsigned short* Asm = SMEM;
    unsigned short* Bsm = SMEM + 128 * LP;

    const int bn = blockIdx.x, bm = blockIdx.y, s = blockIdx.z;
    const int k  = (s < 4) ? r : (KCH - 1 - r);
    const int row0 = bm * 128, c0 = bn * 128;
    const int tid = threadIdx.x;
    const int srow = tid >> 1;

    int aidx = indice[(row0 + srow) * KCH + k]; if (aidx < 0) aidx = 0;
    const float* aX = h_tensor + (size_t)aidx * DM;
    const unsigned short* hs_in = h_in + (size_t)s * N_SEQ * DM;
    const unsigned short* aH = hs_in + (size_t)(row0 + srow) * DM;
    const unsigned short* bR = wcat + ((size_t)s * G4 + c0 + srow) * 512;

    f4 acc[4][4];
#pragma unroll
    for (int i = 0; i < 4; ++i)
#pragma unroll
        for (int j = 0; j < 4; ++j) acc[i][j] = (f4)(0.f);

    mfma_gemm<512, 256>(aX, aH, bR, Asm, Bsm, acc);

    // ---- fused LSTM epilogue ----
    const int lane = tid & 63;
    const int wave = tid >> 6;
    const int wm = (wave >> 1) * 64, wn = (wave & 1) * 64;
    float* sc = (float*)SMEM + wave * (16 * EP);   // 4352 B per wave

    __syncthreads();   // SMEM reuse safe

#pragma unroll
    for (int i = 0; i < 4; ++i) {
        // scatter C-layout tile-i (16 rows x 64 cols) into scratch
#pragma unroll
        for (int j = 0; j < 4; ++j) {
            const int colL = j * 16 + (lane & 15);
            const int rbase = (lane >> 4) * 4;
#pragma unroll
            for (int reg = 0; reg < 4; ++reg)
                sc[(rbase + reg) * EP + colL] = acc[i][j][reg];
        }
        __syncthreads();
        // one lane per cell: row = lane&15, d-slot = (lane>>4)+4q
        const int rowg = row0 + wm + i * 16 + (lane & 15);
        const bool m = (indice[rowg * KCH + k] != -1);
#pragma unroll
        for (int q = 0; q < 4; ++q) {
            const int dL = (lane >> 4) + q * 4;          // 0..15
            const f4 gv = *(const f4*)(sc + (lane & 15) * EP + dL * 4);
            const f4 bb = *(const f4*)(bsumr + s * G4 + c0 + wn + dL * 4);
            const int d = ((c0 + wn) >> 2) + dL;
            const float ii = sigf(gv.x + bb.x);
            const float ff = sigf(gv.y + bb.y);
            const float uu = tanhf(gv.z + bb.z);
            const float oo = sigf(gv.w + bb.w);
            const size_t cix = ((size_t)s * N_SEQ + rowg) * DM + d;
            const float c_old = c_state[cix];
            const float cn = ff * c_old + ii * uu;
            const float cw = m ? cn : c_old;
            c_state[cix] = cw;
            const float hn = oo * tanhf(cn);
            const unsigned short hv = m ? f2bf(hn) : hs_in[(size_t)rowg * DM + d];
            h_out[cix] = hv;   // same flat index as c_state: (s,row,d)
            if (s == 0)
                y_cur[(size_t)rowg * DM + d] = m ? f2bf(hn) : (unsigned short)0;
            else if (s == 4)
                y_cur[(size_t)(N_SEQ + rowg) * DM + d] = m ? f2bf(hn) : (unsigned short)0;
        }
        __syncthreads();
    }
}

// ys0[n, kslice, :] += y_cur[z] @ fcb[z]^T   grid (2, 32, 2), MFMA
__global__ __launch_bounds__(256) void k_acc_fc_mfma(
    const unsigned short* __restrict__ y_cur, const unsigned short* __restrict__ fcb,
    unsigned short* __restrict__ ys0, int r)
{
    __shared__ __align__(16) unsigned short SMEM[2 * 128 * LP];
    const int z = blockIdx.z;
    const int kslice = z ? (KCH - 1 - r) : r;
    const int row0 = blockIdx.y * 128, c0 = blockIdx.x * 128;
    const int tid = threadIdx.x;
    const int srow = tid >> 1;

    const unsigned short* aH = y_cur + ((size_t)z * N_SEQ + row0 + srow) * DM;
    const unsigned short* bR = fcb + ((size_t)z * DM + c0 + srow) * DM;

    f4 acc[4][4];
#pragma unroll
    for (int i = 0; i < 4; ++i)
#pragma unroll
        for (int j = 0; j < 4; ++j) acc[i][j] = (f4)(0.f);

    mfma_gemm<256, 0>(nullptr, aH, bR, SMEM, SMEM + 128 * LP, acc);

    const int lane = tid & 63, wave = tid >> 6;
    const int wm = (wave >> 1) * 64, wn = (wave & 1) * 64;
#pragma unroll
    for (int i = 0; i < 4; ++i)
#pragma unroll
        for (int j = 0; j < 4; ++j) {
            const int col = c0 + wn + j * 16 + (lane & 15);
#pragma unroll
            for (int reg = 0; reg < 4; ++reg) {
                const int rowg = row0 + wm + i * 16 + (lane >> 4) * 4 + reg;
                const size_t ix = ((size_t)rowg * KCH + kslice) * DM + col;
                ys0[ix] = f2bf(bf2f(ys0[ix]) + acc[i][j][reg]);
            }
        }
}

// --------------------------- one-shot fp32 kernels --------------------------

__global__ __launch_bounds__(256) void k_wx(
    const float* __restrict__ x, const float* __restrict__ W_w,
    const float* __restrict__ W_b, unsigned short* __restrict__ Wx)
{
    __shared__ float As[BK][BM + 4];
    __shared__ float Bs[BK][BN + 4];
    const int row0 = blockIdx.y * BM;
    const int colbase = blockIdx.x * BN;
    const int ty = threadIdx.x >> 4, tx = threadIdx.x & 15;

    float acc[8][4];
#pragma unroll
    for (int i = 0; i < 8; ++i)
#pragma unroll
        for (int j = 0; j < 4; ++j) acc[i][j] = 0.f;

    gemm_pass<0, float>(x, DM, nullptr, 0, W_w + (size_t)colbase * DM, DM,
                        acc, As, Bs, row0);
#pragma unroll
    for (int i = 0; i < 8; ++i) {
        const int grow = row0 + ty * 8 + i;
#pragma unroll
        for (int j = 0; j < 4; ++j) {
            const int col = colbase + tx * 4 + j;
            Wx[(size_t)grow * G4 + col] = f2bf(acc[i][j] + W_b[col]);
        }
    }
}

__global__ __launch_bounds__(256) void k_bwd_fused(
    const float* __restrict__ h_tensor, const int* __restrict__ last_idx,
    const float* __restrict__ Wih, const float* __restrict__ hh0,
    const float* __restrict__ c0, unsigned short* __restrict__ yb_last)
{
    __shared__ float As[BK][BM + 4];
    __shared__ float Bs[BK][BN + 4];
    __shared__ unsigned short stash[BM][BN];
    const int jz = blockIdx.z, j = jz + 1, wsel = j * 2 + 1;
    const int row0 = blockIdx.y * BM;
    const int colbase = blockIdx.x * BN;
    const int ty = threadIdx.x >> 4, tx = threadIdx.x & 15;
    const int gate_order[4] = {2, 0, 1, 3};

#pragma unroll
    for (int gg = 0; gg < 4; ++gg) {
        const int gi = gate_order[gg];
        const int gcol = gi * DM + colbase;
        float acc[8][4];
#pragma unroll
        for (int i = 0; i < 8; ++i)
#pragma unroll
            for (int j2 = 0; j2 < 4; ++j2) acc[i][j2] = 0.f;

        gemm_pass<2, float>(h_tensor, DM, last_idx, 0,
                            Wih + ((size_t)wsel * G4 + gcol) * DM, DM,
                            acc, As, Bs, row0);

        const float* bptr = hh0 + (size_t)j * G4 + gcol + tx * 4;
#pragma unroll
        for (int i = 0; i < 8; ++i) {
            const int rr = ty * 8 + i;
            const int grow = row0 + rr;
#pragma unroll
            for (int j2 = 0; j2 < 4; ++j2) {
                const int cc = tx * 4 + j2;
                const int d  = colbase + cc;
                const float gval = acc[i][j2] + bptr[j2];
                if (gg == 0) {
                    stash[rr][cc] = f2bf(tanhf(gval));
                } else if (gg == 1) {
                    stash[rr][cc] = f2bf(sigf(gval) * bf2f(stash[rr][cc]));
                } else if (gg == 2) {
                    const float c_new = sigf(gval) * c0[j * DM + d] + bf2f(stash[rr][cc]);
                    stash[rr][cc] = f2bf(tanhf(c_new));
                } else {
                    const float hn = sigf(gval) * bf2f(stash[rr][cc]);
                    yb_last[((size_t)jz * N_SEQ + grow) * DM + d] = f2bf(hn);
                }
            }
        }
    }
}

__global__ __launch_bounds__(256) void k_fc_last(
    const unsigned short* __restrict__ h_final, const unsigned short* __restrict__ yb_last,
    const float* __restrict__ fc, unsigned short* __restrict__ ys_last)
{
    __shared__ float As[BK][BM + 4];
    __shared__ float Bs[BK][BN + 4];
    const int jz = blockIdx.z, j = jz + 1;
    const float* fcj = fc + (size_t)j * DM * (2 * DM);
    const int row0 = blockIdx.y * BM;
    const int colbase = blockIdx.x * BN;
    const int ty = threadIdx.x >> 4, tx = threadIdx.x & 15;

    float acc[8][4];
#pragma unroll
    for (int i = 0; i < 8; ++i)
#pragma unroll
        for (int j2 = 0; j2 < 4; ++j2) acc[i][j2] = 0.f;

    gemm_pass<0, unsigned short>(h_final + (size_t)(1 + jz) * N_SEQ * DM, DM, nullptr, 0,
                                 fcj + (size_t)colbase * (2 * DM), 2 * DM,
                                 acc, As, Bs, row0);
    gemm_pass<0, unsigned short>(yb_last + (size_t)jz * N_SEQ * DM, DM, nullptr, 0,
                                 fcj + (size_t)colbase * (2 * DM) + DM, 2 * DM,
                                 acc, As, Bs, row0);
#pragma unroll
    for (int i = 0; i < 8; ++i) {
        const int grow = row0 + ty * 8 + i;
#pragma unroll
        for (int j2 = 0; j2 < 4; ++j2)
            ys_last[((size_t)jz * N_SEQ + grow) * DM + colbase + tx * 4 + j2] = f2bf(acc[i][j2]);
    }
}

__global__ __launch_bounds__(256) void k_final(
    const unsigned short* __restrict__ Wx, const unsigned short* __restrict__ ys0,
    const unsigned short* __restrict__ ys_last, const float* __restrict__ c_tensor,
    const int* __restrict__ indice, float* __restrict__ out)
{
    const int n = blockIdx.x, d = threadIdx.x;
    const float Wf = bf2f(Wx[(size_t)n * G4 + d]);
    const float Wi = bf2f(Wx[(size_t)n * G4 + DM + d]);
    const float Wu = bf2f(Wx[(size_t)n * G4 + 2 * DM + d]);
    const float Wo = bf2f(Wx[(size_t)n * G4 + 3 * DM + d]);
    float bf = 0.f;
#pragma unroll
    for (int k = 0; k < KCH; ++k) {
        const int id = indice[n * KCH + k];
        if (id >= 0)
            bf += sigf(Wf + bf2f(ys0[((size_t)n * KCH + k) * DM + d])) *
                  c_tensor[(size_t)id * DM + d];
    }
    const float bi = sigf(bf2f(ys_last[((size_t)0 * N_SEQ + n) * DM + d]) + Wi);
    const float bu = tanhf(bf2f(ys_last[((size_t)1 * N_SEQ + n) * DM + d]) + Wu);
    const float bo = sigf(bf2f(ys_last[((size_t)2 * N_SEQ + n) * DM + d]) + Wo);
    const float nc = bi * bu + bf;
    const float nh = bo * tanhf(nc);
    out[(size_t)n * DM + d] = nh;
    out[(size_t)N_SEQ * DM + (size_t)n * DM + d] = nc;
}

// --------------------------- launcher ---------------------------------------
extern "C" void kernel_launch(void* const* d_in, const int* in_sizes, int n_in,
                              void* d_out, int out_size, void* d_ws, size_t ws_size,
                              hipStream_t stream)
{
    const float* x        = (const float*)d_in[0];
    const float* h_tensor = (const float*)d_in[1];
    const float* c_tensor = (const float*)d_in[2];
    const int*   indice   = (const int*)d_in[3];
    const float* W_w      = (const float*)d_in[4];
    const float* W_b      = (const float*)d_in[5];
    const float* h0       = (const float*)d_in[6];
    const float* c0       = (const float*)d_in[7];
    const float* Wih      = (const float*)d_in[8];
    const float* Whh      = (const float*)d_in[9];
    const float* bih      = (const float*)d_in[10];
    const float* bhh      = (const float*)d_in[11];
    const float* fc       = (const float*)d_in[12];
    float* out = (float*)d_out;

    // ---- workspace layout (aliasing: see comments; need = 95,473,664 B) ----
    char* base = (char*)d_ws;
    float*          c_state  = (float*)(base + 0);               // 20,971,520
    float*          hh0      = (float*)(base + 20971520);        //     16,384
    int*            last_idx = (int*)  (base + 20987904);        //     16,384
    float*          bsumr    = (float*)(base + 21004288);        //     20,480
    unsigned short* hA       = (unsigned short*)(base + 21024768);   // 10,485,760
    unsigned short* hB       = (unsigned short*)(base + 31510528);   // 10,485,760
    unsigned short* ys0      = (unsigned short*)(base + 41996288);   // 33,554,432
    unsigned short* WxBuf    = (unsigned short*)(base + 75550720);   //  8,388,608
    unsigned short* ybBuf    = (unsigned short*)(base + 83939328);   //  6,291,456
    unsigned short* wcat     = (unsigned short*)(base + 90230784);   //  5,242,880
    const size_t need = 95473664;
    if (ws_size < need) return;   // diagnostic: zero-output absmax fail

    // aliases (disjoint lifetimes):
    unsigned short* y_cur   = WxBuf;   // rounds only; Wx computed after rounds
    unsigned short* fcb     = ybBuf;   // rounds only; yb_last written after
    unsigned short* ys_last = hB;      // post-rounds; final h lives in hA
    unsigned short* yb_last = ybBuf;

    k_lastidx<<<16, 256, 0, stream>>>(indice, last_idx);
    k_hh0<<<3, 1024, 0, stream>>>(bih, bhh, h0, Whh, hh0);
    k_init_states<<<5 * N_SEQ, 256, 0, stream>>>(h0, c0, hA, c_state);
    k_zero4<<<8192, 256, 0, stream>>>((float4*)ys0);
    k_prep_wcat<<<dim3(G4, 5), 256, 0, stream>>>(Wih, Whh, bih, bhh, wcat, bsumr);
    k_prep_fcb<<<dim3(DM, 2), 256, 0, stream>>>(fc, fcb);

    for (int r = 0; r < KCH; ++r) {
        const unsigned short* h_in = (r & 1) ? hB : hA;
        unsigned short* h_out      = (r & 1) ? hA : hB;
        k_scan_mfma<<<dim3(8, 32, 5), 256, 0, stream>>>(
            h_tensor, indice, h_in, h_out, c_state, wcat, bsumr, y_cur, r);
        k_acc_fc_mfma<<<dim3(2, 32, 2), 256, 0, stream>>>(y_cur, fcb, ys0, r);
    }
    // r=15 odd -> final h in hA; y_cur & fcb now dead.

    k_bwd_fused<<<dim3(4, 32, 3), 256, 0, stream>>>(
        h_tensor, last_idx, Wih, hh0, c0, yb_last);
    k_wx<<<dim3(16, 32), 256, 0, stream>>>(x, W_w, W_b, WxBuf);
    k_fc_last<<<dim3(4, 32, 3), 256, 0, stream>>>(hA, yb_last, fc, ys_last);

    k_final<<<N_SEQ, 256, 0, stream>>>(WxBuf, ys0, ys_last, c_tensor, indice, out);
}

// Round 5
// 1811.892 us; speedup vs baseline: 5.8829x; 1.1095x over previous
//
#include <hip/hip_runtime.h>
#include <math.h>

#define N_SEQ 4096
#define KCH   16
#define DM    256
#define G4    1024
// MFMA LDS pitch: 32 k bf16 (64B) + 16B pad = 80B = 40 ushorts
#define LP    40
#define EP    68   // epilogue scratch pitch in floats

typedef __attribute__((ext_vector_type(8))) short bf8;
typedef __attribute__((ext_vector_type(4))) float f4;

__device__ __forceinline__ float fast_rcp(float x) { return __builtin_amdgcn_rcpf(x); }
__device__ __forceinline__ float sigf(float x)   { return fast_rcp(1.f + __expf(-x)); }
__device__ __forceinline__ float tanh_f(float x) { return 1.f - 2.f * fast_rcp(1.f + __expf(2.f * x)); }

__device__ __forceinline__ float bf2f(unsigned short u) {
    return __uint_as_float(((unsigned)u) << 16);
}
__device__ __forceinline__ unsigned short f2bf(float f) {
    unsigned u = __float_as_uint(f);
    unsigned r = (u + 0x7fffu + ((u >> 16) & 1u)) >> 16;   // RNE
    return (unsigned short)r;
}
__device__ __forceinline__ unsigned pack2(float a, float b) {
    return (unsigned)f2bf(a) | ((unsigned)f2bf(b) << 16);
}

// ===========================================================================
// MFMA K-pass: acc[4][4] += A[128,KLEN] @ B[128,KLEN]^T (bf16 x bf16 -> f32)
// aRow/bRow: per-thread row base pointers (row = tid>>1), k advances inside.
// 256 thr = 4 waves in 2x2 of 64x64. LDS rows padded to 80 B.
// ===========================================================================
template<int KLEN>
__device__ __forceinline__ void pass_bf(
    const unsigned short* __restrict__ aRow,
    const unsigned short* __restrict__ bRow,
    unsigned short* Asm, unsigned short* Bsm, f4 (&acc)[4][4])
{
    const int tid  = threadIdx.x;
    const int kh   = (tid & 1) * 16;
    const int srow = tid >> 1;
    const int lane = tid & 63, wave = tid >> 6;
    const int wm = (wave >> 1) * 64, wn = (wave & 1) * 64;
    const int fr = lane & 15, fk = (lane >> 4) * 8;
    unsigned short* da = Asm + srow * LP + kh;
    unsigned short* db = Bsm + srow * LP + kh;

    for (int k0 = 0; k0 < KLEN; k0 += 32) {
        __syncthreads();
        *(int4*)(da)     = *(const int4*)(aRow + k0 + kh);
        *(int4*)(da + 8) = *(const int4*)(aRow + k0 + kh + 8);
        *(int4*)(db)     = *(const int4*)(bRow + k0 + kh);
        *(int4*)(db + 8) = *(const int4*)(bRow + k0 + kh + 8);
        __syncthreads();
        bf8 af[4], bb[4];
#pragma unroll
        for (int i = 0; i < 4; ++i)
            af[i] = *(const bf8*)(Asm + (wm + i * 16 + fr) * LP + fk);
#pragma unroll
        for (int j = 0; j < 4; ++j)
            bb[j] = *(const bf8*)(Bsm + (wn + j * 16 + fr) * LP + fk);
#pragma unroll
        for (int i = 0; i < 4; ++i)
#pragma unroll
            for (int j = 0; j < 4; ++j)
                acc[i][j] = __builtin_amdgcn_mfma_f32_16x16x32_bf16(
                    af[i], bb[j], acc[i][j], 0, 0, 0);
    }
}

// Same, but A rows are fp32 (converted to bf16 during staging).
template<int KLEN>
__device__ __forceinline__ void pass_f32(
    const float* __restrict__ aRow,
    const unsigned short* __restrict__ bRow,
    unsigned short* Asm, unsigned short* Bsm, f4 (&acc)[4][4])
{
    const int tid  = threadIdx.x;
    const int kh   = (tid & 1) * 16;
    const int srow = tid >> 1;
    const int lane = tid & 63, wave = tid >> 6;
    const int wm = (wave >> 1) * 64, wn = (wave & 1) * 64;
    const int fr = lane & 15, fk = (lane >> 4) * 8;
    unsigned short* da = Asm + srow * LP + kh;
    unsigned short* db = Bsm + srow * LP + kh;

    for (int k0 = 0; k0 < KLEN; k0 += 32) {
        __syncthreads();
        {
            const float* s = aRow + k0 + kh;
            float4 v0 = *(const float4*)(s);
            float4 v1 = *(const float4*)(s + 4);
            float4 v2 = *(const float4*)(s + 8);
            float4 v3 = *(const float4*)(s + 12);
            *(int4*)(da)     = make_int4(pack2(v0.x, v0.y), pack2(v0.z, v0.w),
                                         pack2(v1.x, v1.y), pack2(v1.z, v1.w));
            *(int4*)(da + 8) = make_int4(pack2(v2.x, v2.y), pack2(v2.z, v2.w),
                                         pack2(v3.x, v3.y), pack2(v3.z, v3.w));
        }
        *(int4*)(db)     = *(const int4*)(bRow + k0 + kh);
        *(int4*)(db + 8) = *(const int4*)(bRow + k0 + kh + 8);
        __syncthreads();
        bf8 af[4], bb[4];
#pragma unroll
        for (int i = 0; i < 4; ++i)
            af[i] = *(const bf8*)(Asm + (wm + i * 16 + fr) * LP + fk);
#pragma unroll
        for (int j = 0; j < 4; ++j)
            bb[j] = *(const bf8*)(Bsm + (wn + j * 16 + fr) * LP + fk);
#pragma unroll
        for (int i = 0; i < 4; ++i)
#pragma unroll
            for (int j = 0; j < 4; ++j)
                acc[i][j] = __builtin_amdgcn_mfma_f32_16x16x32_bf16(
                    af[i], bb[j], acc[i][j], 0, 0, 0);
    }
}

// --------------------------- setup kernels ----------------------------------

__global__ __launch_bounds__(256) void k_lastidx(
    const int* __restrict__ indice, int* __restrict__ last_idx)
{
    const int n = blockIdx.x * 256 + threadIdx.x;
    if (n >= N_SEQ) return;
    int len = 0;
#pragma unroll
    for (int k = 0; k < KCH; ++k) len += (indice[n * KCH + k] != -1);
    last_idx[n] = indice[n * KCH + (len - 1)];
}

// bsum2[jz][c=d*4+g] = bih+bhh+h0[j]@Whh[j,1] row (g*256+d)   (trees 1..3)
__global__ __launch_bounds__(1024) void k_hh0_bsum2(
    const float* __restrict__ bih, const float* __restrict__ bhh,
    const float* __restrict__ h0, const float* __restrict__ Whh,
    float* __restrict__ bsum2)
{
    const int jz = blockIdx.x, j = jz + 1;
    const int g = threadIdx.x;              // gate-dim index: gate*256 + d
    const int jd = j * 2 + 1;
    const float* wrow = Whh + ((size_t)jd * G4 + g) * DM;
    float s = bih[jd * G4 + g] + bhh[jd * G4 + g];
    for (int h = 0; h < DM; ++h) s = fmaf(h0[j * DM + h], wrow[h], s);
    const int c = (g & 255) * 4 + (g >> 8);
    bsum2[jz * G4 + c] = s;
}

__global__ __launch_bounds__(256) void k_init_states(
    const float* __restrict__ h0, const float* __restrict__ c0,
    unsigned short* __restrict__ hA, float* __restrict__ c_state)
{
    const int row = blockIdx.x;             // 0 .. 5*N_SEQ-1
    const int s = row >> 12;
    const int tree = (s < 4) ? s : 0;
    const int d = threadIdx.x;
    hA[(size_t)row * DM + d]      = f2bf(h0[tree * DM + d]);
    c_state[(size_t)row * DM + d] = c0[tree * DM + d];
}

__global__ __launch_bounds__(256) void k_zero4(float4* __restrict__ p)
{
    p[(size_t)blockIdx.x * 256 + threadIdx.x] = make_float4(0.f, 0.f, 0.f, 0.f);
}

// Wcat[s][c=d*4+g][0:256]=Wih row(g*256+d); [256:512]=Whh row. + bsumr.
__global__ __launch_bounds__(256) void k_prep_wcat(
    const float* __restrict__ Wih, const float* __restrict__ Whh,
    const float* __restrict__ bih, const float* __restrict__ bhh,
    unsigned short* __restrict__ wcat, float* __restrict__ bsumr)
{
    const int c = blockIdx.x, s = blockIdx.y;
    const int wsel = (s < 4) ? s * 2 : 1;
    const int d = c >> 2, g = c & 3;
    const size_t srcrow = ((size_t)wsel * G4 + g * DM + d) * DM;
    unsigned short* dst = wcat + ((size_t)s * G4 + c) * 512;
    const int t = threadIdx.x;
    dst[t]       = f2bf(Wih[srcrow + t]);
    dst[256 + t] = f2bf(Whh[srcrow + t]);
    if (t == 0)
        bsumr[s * G4 + c] = bih[wsel * G4 + g * DM + d] + bhh[wsel * G4 + g * DM + d];
}

// wcat2[jz][c=d*4+g][k] = Wih[j,1] row(g*256+d)  (trees 1..3, bwd dir)
__global__ __launch_bounds__(256) void k_prep_wcat2(
    const float* __restrict__ Wih, unsigned short* __restrict__ wcat2)
{
    const int c = blockIdx.x, jz = blockIdx.y, j = jz + 1;
    const int d = c >> 2, g = c & 3;
    const size_t srcrow = ((size_t)(j * 2 + 1) * G4 + g * DM + d) * DM;
    wcat2[((size_t)jz * G4 + c) * 256 + threadIdx.x] = f2bf(Wih[srcrow + threadIdx.x]);
}

// fcb[z][dout][k] = fc[0][dout][z*256+k]  (tree-0 rounds)
__global__ __launch_bounds__(256) void k_prep_fcb(
    const float* __restrict__ fc, unsigned short* __restrict__ fcb)
{
    const int dout = blockIdx.x, z = blockIdx.y, t = threadIdx.x;
    fcb[((size_t)z * DM + dout) * DM + t] = f2bf(fc[(size_t)dout * 512 + z * DM + t]);
}

// fcb2[jz][dout][0:512] = fc[j][dout][:]  (trees 1..3)
__global__ __launch_bounds__(256) void k_prep_fcb2(
    const float* __restrict__ fc, unsigned short* __restrict__ fcb2)
{
    const int dout = blockIdx.x, jz = blockIdx.y, j = jz + 1, t = threadIdx.x;
    const float* src = fc + ((size_t)j * DM + dout) * 512;
    unsigned short* dst = fcb2 + ((size_t)jz * DM + dout) * 512;
    dst[t]       = f2bf(src[t]);
    dst[t + 256] = f2bf(src[t + 256]);
}

__global__ __launch_bounds__(256) void k_prep_wwb(
    const float* __restrict__ W_w, unsigned short* __restrict__ wwb)
{
    const size_t i = (size_t)blockIdx.x * 256 + threadIdx.x;
    wwb[i] = f2bf(W_w[i]);
}

// gather one x-slice: xbuf[zz][n][:] = bf16(h_tensor[indice_safe[n,kk]][:])
__device__ __forceinline__ void gather_slice(
    const float* __restrict__ h_tensor, const int* __restrict__ indice,
    unsigned short* __restrict__ xbuf, int zz, int kk, int blk)
{
    const int row = blk * 64 + (threadIdx.x >> 2);
    const int cb  = (threadIdx.x & 3) * 64;
    int idx = indice[row * KCH + kk]; if (idx < 0) idx = 0;
    const float* src = h_tensor + (size_t)idx * DM + cb;
    unsigned short* dst = xbuf + ((size_t)zz * N_SEQ + row) * DM + cb;
#pragma unroll
    for (int c = 0; c < 64; c += 4) {
        float4 v = *(const float4*)(src + c);
        *(uint2*)(dst + c) = make_uint2(pack2(v.x, v.y), pack2(v.z, v.w));
    }
}

// round-0 x slices: z0 -> k=0, z1 -> k=15.  grid(128)
__global__ __launch_bounds__(256) void k_gather_x0(
    const float* __restrict__ h_tensor, const int* __restrict__ indice,
    unsigned short* __restrict__ xbuf)
{
    const int slice = blockIdx.x >> 6, blk = blockIdx.x & 63;
    gather_slice(h_tensor, indice, xbuf, slice, slice ? (KCH - 1) : 0, blk);
}

// --------------------------- MFMA scan round --------------------------------
// grid (8, 32, 5). Block: rows [bm*128), interleaved gate-cols [bn*128) =
// 32 d-values x 4 gates. Fused LSTM epilogue via per-wave LDS transpose.
__global__ __launch_bounds__(256) void k_scan_mfma(
    const unsigned short* __restrict__ xbuf, const int* __restrict__ indice,
    const unsigned short* __restrict__ h_in, unsigned short* __restrict__ h_out,
    float* __restrict__ c_state,
    const unsigned short* __restrict__ wcat, const float* __restrict__ bsumr,
    unsigned short* __restrict__ y_cur, int r)
{
    __shared__ __align__(16) unsigned short SMEM[2 * 128 * LP];  // 20480 B
    unsigned short* Asm = SMEM;
    unsigned short* Bsm = SMEM + 128 * LP;

    const int s  = blockIdx.z;
    const int k  = (s < 4) ? r : (KCH - 1 - r);
    const int z  = (s < 4) ? 0 : 1;
    const int row0 = blockIdx.y * 128, c0 = blockIdx.x * 128;
    const int tid = threadIdx.x;
    const int srow = tid >> 1;

    const unsigned short* aX = xbuf + ((size_t)z * N_SEQ + row0 + srow) * DM;
    const unsigned short* hs_in = h_in + (size_t)s * N_SEQ * DM;
    const unsigned short* aH = hs_in + (size_t)(row0 + srow) * DM;
    const unsigned short* bR = wcat + ((size_t)s * G4 + c0 + srow) * 512;

    f4 acc[4][4];
#pragma unroll
    for (int i = 0; i < 4; ++i)
#pragma unroll
        for (int j = 0; j < 4; ++j) acc[i][j] = (f4)(0.f);

    pass_bf<256>(aX, bR, Asm, Bsm, acc);
    pass_bf<256>(aH, bR + 256, Asm, Bsm, acc);

    // ---- fused LSTM epilogue ----
    const int lane = tid & 63, wave = tid >> 6;
    const int wm = (wave >> 1) * 64, wn = (wave & 1) * 64;
    float* sc = (float*)SMEM + wave * (16 * EP);

    __syncthreads();
#pragma unroll
    for (int i = 0; i < 4; ++i) {
#pragma unroll
        for (int j = 0; j < 4; ++j) {
            const int colL = j * 16 + (lane & 15);
            const int rbase = (lane >> 4) * 4;
#pragma unroll
            for (int reg = 0; reg < 4; ++reg)
                sc[(rbase + reg) * EP + colL] = acc[i][j][reg];
        }
        __syncthreads();
        const int rowg = row0 + wm + i * 16 + (lane & 15);
        const bool m = (indice[rowg * KCH + k] != -1);
#pragma unroll
        for (int q = 0; q < 4; ++q) {
            const int dL = (lane >> 4) + q * 4;
            const f4 gv = *(const f4*)(sc + (lane & 15) * EP + dL * 4);
            const f4 bb = *(const f4*)(bsumr + s * G4 + c0 + wn + dL * 4);
            const int d = ((c0 + wn) >> 2) + dL;
            const float ii = sigf(gv.x + bb.x);
            const float ff = sigf(gv.y + bb.y);
            const float uu = tanh_f(gv.z + bb.z);
            const float oo = sigf(gv.w + bb.w);
            const size_t cix = ((size_t)s * N_SEQ + rowg) * DM + d;
            const float c_old = c_state[cix];
            const float cn = ff * c_old + ii * uu;
            const float cw = m ? cn : c_old;
            c_state[cix] = cw;
            const float hn = oo * tanh_f(cn);
            const unsigned short hv = m ? f2bf(hn) : hs_in[(size_t)rowg * DM + d];
            h_out[cix] = hv;
            if (s == 0)
                y_cur[(size_t)rowg * DM + d] = m ? f2bf(hn) : (unsigned short)0;
            else if (s == 4)
                y_cur[(size_t)(N_SEQ + rowg) * DM + d] = m ? f2bf(hn) : (unsigned short)0;
        }
        __syncthreads();
    }
}

// z<2: ys0[n,kslice,:] += y_cur[z] @ fcb[z]^T ; z>=2: gather x slices for r+1
// grid (2, 32, 4)
__global__ __launch_bounds__(256) void k_acc_fc_mfma(
    const unsigned short* __restrict__ y_cur, const unsigned short* __restrict__ fcb,
    unsigned short* __restrict__ ys0, unsigned short* __restrict__ xbuf,
    const float* __restrict__ h_tensor, const int* __restrict__ indice, int r)
{
    const int z = blockIdx.z;
    if (z >= 2) {
        const int rr = r + 1;
        if (rr >= KCH) return;
        const int zz = z - 2;
        gather_slice(h_tensor, indice, xbuf, zz, zz ? (KCH - 1 - rr) : rr,
                     blockIdx.y * 2 + blockIdx.x);
        return;
    }
    __shared__ __align__(16) unsigned short SMEM[2 * 128 * LP];
    const int kslice = z ? (KCH - 1 - r) : r;
    const int row0 = blockIdx.y * 128, c0 = blockIdx.x * 128;
    const int tid = threadIdx.x;
    const int srow = tid >> 1;

    const unsigned short* aH = y_cur + ((size_t)z * N_SEQ + row0 + srow) * DM;
    const unsigned short* bR = fcb + ((size_t)z * DM + c0 + srow) * DM;

    f4 acc[4][4];
#pragma unroll
    for (int i = 0; i < 4; ++i)
#pragma unroll
        for (int j = 0; j < 4; ++j) acc[i][j] = (f4)(0.f);

    pass_bf<256>(aH, bR, SMEM, SMEM + 128 * LP, acc);

    const int lane = tid & 63, wave = tid >> 6;
    const int wm = (wave >> 1) * 64, wn = (wave & 1) * 64;
#pragma unroll
    for (int i = 0; i < 4; ++i)
#pragma unroll
        for (int j = 0; j < 4; ++j) {
            const int col = c0 + wn + j * 16 + (lane & 15);
#pragma unroll
            for (int reg = 0; reg < 4; ++reg) {
                const int rowg = row0 + wm + i * 16 + (lane >> 4) * 4 + reg;
                const size_t ix = ((size_t)rowg * KCH + kslice) * DM + col;
                ys0[ix] = f2bf(bf2f(ys0[ix]) + acc[i][j][reg]);
            }
        }
}

// --------------------------- post-round MFMA kernels ------------------------

// Backward single step, trees 1..3. grid (8, 32, 3).
__global__ __launch_bounds__(256) void k_bwd_mfma(
    const float* __restrict__ h_tensor, const int* __restrict__ last_idx,
    const unsigned short* __restrict__ wcat2, const float* __restrict__ bsum2,
    const float* __restrict__ c0, unsigned short* __restrict__ yb_last)
{
    __shared__ __align__(16) unsigned short SMEM[2 * 128 * LP];
    const int jz = blockIdx.z, j = jz + 1;
    const int row0 = blockIdx.y * 128, c0t = blockIdx.x * 128;
    const int tid = threadIdx.x;
    const int srow = tid >> 1;

    const float* aF = h_tensor + (size_t)last_idx[row0 + srow] * DM;
    const unsigned short* bR = wcat2 + ((size_t)jz * G4 + c0t + srow) * 256;

    f4 acc[4][4];
#pragma unroll
    for (int i = 0; i < 4; ++i)
#pragma unroll
        for (int jj = 0; jj < 4; ++jj) acc[i][jj] = (f4)(0.f);

    pass_f32<256>(aF, bR, SMEM, SMEM + 128 * LP, acc);

    const int lane = tid & 63, wave = tid >> 6;
    const int wm = (wave >> 1) * 64, wn = (wave & 1) * 64;
    float* sc = (float*)SMEM + wave * (16 * EP);

    __syncthreads();
#pragma unroll
    for (int i = 0; i < 4; ++i) {
#pragma unroll
        for (int jj = 0; jj < 4; ++jj) {
            const int colL = jj * 16 + (lane & 15);
            const int rbase = (lane >> 4) * 4;
#pragma unroll
            for (int reg = 0; reg < 4; ++reg)
                sc[(rbase + reg) * EP + colL] = acc[i][jj][reg];
        }
        __syncthreads();
        const int rowg = row0 + wm + i * 16 + (lane & 15);
#pragma unroll
        for (int q = 0; q < 4; ++q) {
            const int dL = (lane >> 4) + q * 4;
            const f4 gv = *(const f4*)(sc + (lane & 15) * EP + dL * 4);
            const f4 bb = *(const f4*)(bsum2 + jz * G4 + c0t + wn + dL * 4);
            const int d = ((c0t + wn) >> 2) + dL;
            const float ii = sigf(gv.x + bb.x);
            const float ff = sigf(gv.y + bb.y);
            const float uu = tanh_f(gv.z + bb.z);
            const float oo = sigf(gv.w + bb.w);
            const float cn = ff * c0[j * DM + d] + ii * uu;
            yb_last[((size_t)jz * N_SEQ + rowg) * DM + d] = f2bf(oo * tanh_f(cn));
        }
        __syncthreads();
    }
}

// Wx = x @ W_w^T + W_b (bf16 out).  grid (8, 32).
__global__ __launch_bounds__(256) void k_wx_mfma(
    const float* __restrict__ x, const unsigned short* __restrict__ wwb,
    const float* __restrict__ W_b, unsigned short* __restrict__ Wx)
{
    __shared__ __align__(16) unsigned short SMEM[2 * 128 * LP];
    const int row0 = blockIdx.y * 128, c0 = blockIdx.x * 128;
    const int tid = threadIdx.x;
    const int srow = tid >> 1;

    const float* aF = x + (size_t)(row0 + srow) * DM;
    const unsigned short* bR = wwb + (size_t)(c0 + srow) * DM;

    f4 acc[4][4];
#pragma unroll
    for (int i = 0; i < 4; ++i)
#pragma unroll
        for (int j = 0; j < 4; ++j) acc[i][j] = (f4)(0.f);

    pass_f32<256>(aF, bR, SMEM, SMEM + 128 * LP, acc);

    const int lane = tid & 63, wave = tid >> 6;
    const int wm = (wave >> 1) * 64, wn = (wave & 1) * 64;
#pragma unroll
    for (int i = 0; i < 4; ++i)
#pragma unroll
        for (int j = 0; j < 4; ++j) {
            const int col = c0 + wn + j * 16 + (lane & 15);
            const float bv = W_b[col];
#pragma unroll
            for (int reg = 0; reg < 4; ++reg) {
                const int rowg = row0 + wm + i * 16 + (lane >> 4) * 4 + reg;
                Wx[(size_t)rowg * G4 + col] = f2bf(acc[i][j][reg] + bv);
            }
        }
}

// ys_last[jz] = h_final[1+jz]@fcj[:, :256]^T + yb_last[jz]@fcj[:,256:]^T
// grid (2, 32, 3).
__global__ __launch_bounds__(256) void k_fc_last_mfma(
    const unsigned short* __restrict__ h_final, const unsigned short* __restrict__ yb_last,
    const unsigned short* __restrict__ fcb2, unsigned short* __restrict__ ys_last)
{
    __shared__ __align__(16) unsigned short SMEM[2 * 128 * LP];
    const int jz = blockIdx.z;
    const int row0 = blockIdx.y * 128, c0 = blockIdx.x * 128;
    const int tid = threadIdx.x;
    const int srow = tid >> 1;

    const unsigned short* aH1 = h_final + ((size_t)(1 + jz) * N_SEQ + row0 + srow) * DM;
    const unsigned short* aH2 = yb_last + ((size_t)jz * N_SEQ + row0 + srow) * DM;
    const unsigned short* bR  = fcb2 + ((size_t)jz * DM + c0 + srow) * 512;

    f4 acc[4][4];
#pragma unroll
    for (int i = 0; i < 4; ++i)
#pragma unroll
        for (int j = 0; j < 4; ++j) acc[i][j] = (f4)(0.f);

    pass_bf<256>(aH1, bR, SMEM, SMEM + 128 * LP, acc);
    pass_bf<256>(aH2, bR + 256, SMEM, SMEM + 128 * LP, acc);

    const int lane = tid & 63, wave = tid >> 6;
    const int wm = (wave >> 1) * 64, wn = (wave & 1) * 64;
#pragma unroll
    for (int i = 0; i < 4; ++i)
#pragma unroll
        for (int j = 0; j < 4; ++j) {
            const int col = c0 + wn + j * 16 + (lane & 15);
#pragma unroll
            for (int reg = 0; reg < 4; ++reg) {
                const int rowg = row0 + wm + i * 16 + (lane >> 4) * 4 + reg;
                ys_last[((size_t)jz * N_SEQ + rowg) * DM + col] = f2bf(acc[i][j][reg]);
            }
        }
}

// Final combine -> (new_h, new_c)
__global__ __launch_bounds__(256) void k_final(
    const unsigned short* __restrict__ Wx, const unsigned short* __restrict__ ys0,
    const unsigned short* __restrict__ ys_last, const float* __restrict__ c_tensor,
    const int* __restrict__ indice, float* __restrict__ out)
{
    const int n = blockIdx.x, d = threadIdx.x;
    const float Wf = bf2f(Wx[(size_t)n * G4 + d]);
    const float Wi = bf2f(Wx[(size_t)n * G4 + DM + d]);
    const float Wu = bf2f(Wx[(size_t)n * G4 + 2 * DM + d]);
    const float Wo = bf2f(Wx[(size_t)n * G4 + 3 * DM + d]);
    float bf = 0.f;
#pragma unroll
    for (int k = 0; k < KCH; ++k) {
        const int id = indice[n * KCH + k];
        if (id >= 0)
            bf += sigf(Wf + bf2f(ys0[((size_t)n * KCH + k) * DM + d])) *
                  c_tensor[(size_t)id * DM + d];
    }
    const float bi = sigf(bf2f(ys_last[((size_t)0 * N_SEQ + n) * DM + d]) + Wi);
    const float bu = tanh_f(bf2f(ys_last[((size_t)1 * N_SEQ + n) * DM + d]) + Wu);
    const float bo = sigf(bf2f(ys_last[((size_t)2 * N_SEQ + n) * DM + d]) + Wo);
    const float nc = bi * bu + bf;
    const float nh = bo * tanh_f(nc);
    out[(size_t)n * DM + d] = nh;
    out[(size_t)N_SEQ * DM + (size_t)n * DM + d] = nc;
}

// --------------------------- launcher ---------------------------------------
extern "C" void kernel_launch(void* const* d_in, const int* in_sizes, int n_in,
                              void* d_out, int out_size, void* d_ws, size_t ws_size,
                              hipStream_t stream)
{
    const float* x        = (const float*)d_in[0];
    const float* h_tensor = (const float*)d_in[1];
    const float* c_tensor = (const float*)d_in[2];
    const int*   indice   = (const int*)d_in[3];
    const float* W_w      = (const float*)d_in[4];
    const float* W_b      = (const float*)d_in[5];
    const float* h0       = (const float*)d_in[6];
    const float* c0       = (const float*)d_in[7];
    const float* Wih      = (const float*)d_in[8];
    const float* Whh      = (const float*)d_in[9];
    const float* bih      = (const float*)d_in[10];
    const float* bhh      = (const float*)d_in[11];
    const float* fc       = (const float*)d_in[12];
    float* out = (float*)d_out;

    // ---- workspace layout; need = 98,369,536 B (proven budget >= 100.73 MB)
    char* base = (char*)d_ws;
    float*          c_state  = (float*)(base + 0);                   // 20,971,520
    int*            last_idx = (int*)  (base + 20987904);            //     16,384
    float*          bsumr    = (float*)(base + 21004288);            //     20,480
    unsigned short* hA       = (unsigned short*)(base + 21024768);   // 10,485,760
    unsigned short* hB       = (unsigned short*)(base + 31510528);   // 10,485,760
    unsigned short* ys0      = (unsigned short*)(base + 41996288);   // 33,554,432
    unsigned short* WxBuf    = (unsigned short*)(base + 75550720);   //  8,388,608
    unsigned short* ybBuf    = (unsigned short*)(base + 83939328);   //  6,291,456
    unsigned short* wcat     = (unsigned short*)(base + 90230784);   //  5,242,880
    unsigned short* wcat2    = (unsigned short*)(base + 95473664);   //  1,572,864
    unsigned short* fcb2     = (unsigned short*)(base + 97046528);   //    786,432
    unsigned short* wwb      = (unsigned short*)(base + 97832960);   //    524,288
    float*          bsum2    = (float*)(base + 98357248);            //     12,288
    const size_t need = 98369536;
    if (ws_size < need) return;   // diagnostic: zero-output absmax fail

    // aliases (disjoint lifetimes):
    unsigned short* y_cur   = WxBuf;                 // rounds only
    unsigned short* xbuf    = WxBuf + 2097152;       // rounds only (4 MB)
    unsigned short* fcb     = ybBuf;                 // rounds only (256 KB)
    unsigned short* yb_last = ybBuf;                 // post-rounds
    unsigned short* ys_last = hB;                    // post-rounds (final h in hA)

    k_lastidx<<<16, 256, 0, stream>>>(indice, last_idx);
    k_hh0_bsum2<<<3, 1024, 0, stream>>>(bih, bhh, h0, Whh, bsum2);
    k_init_states<<<5 * N_SEQ, 256, 0, stream>>>(h0, c0, hA, c_state);
    k_zero4<<<8192, 256, 0, stream>>>((float4*)ys0);
    k_prep_wcat<<<dim3(G4, 5), 256, 0, stream>>>(Wih, Whh, bih, bhh, wcat, bsumr);
    k_prep_wcat2<<<dim3(G4, 3), 256, 0, stream>>>(Wih, wcat2);
    k_prep_fcb<<<dim3(DM, 2), 256, 0, stream>>>(fc, fcb);
    k_prep_fcb2<<<dim3(DM, 3), 256, 0, stream>>>(fc, fcb2);
    k_prep_wwb<<<1024, 256, 0, stream>>>(W_w, wwb);
    k_gather_x0<<<128, 256, 0, stream>>>(h_tensor, indice, xbuf);

    for (int r = 0; r < KCH; ++r) {
        const unsigned short* h_in = (r & 1) ? hB : hA;
        unsigned short* h_out      = (r & 1) ? hA : hB;
        k_scan_mfma<<<dim3(8, 32, 5), 256, 0, stream>>>(
            xbuf, indice, h_in, h_out, c_state, wcat, bsumr, y_cur, r);
        k_acc_fc_mfma<<<dim3(2, 32, 4), 256, 0, stream>>>(
            y_cur, fcb, ys0, xbuf, h_tensor, indice, r);
    }
    // r=15 odd -> final h in hA; y_cur/xbuf/fcb now dead.

    k_bwd_mfma<<<dim3(8, 32, 3), 256, 0, stream>>>(
        h_tensor, last_idx, wcat2, bsum2, c0, yb_last);
    k_wx_mfma<<<dim3(8, 32), 256, 0, stream>>>(x, wwb, W_b, WxBuf);
    k_fc_last_mfma<<<dim3(2, 32, 3), 256, 0, stream>>>(hA, yb_last, fcb2, ys_last);

    k_final<<<N_SEQ, 256, 0, stream>>>(WxBuf, ys0, ys_last, c_tensor, indice, out);
}

// Round 6
// 1505.005 us; speedup vs baseline: 7.0825x; 1.2039x over previous
//
#include <hip/hip_runtime.h>
#include <math.h>

#define N_SEQ 4096
#define KCH   16
#define DM    256
#define G4    1024
// padded-LDS pitch for the legacy post-round kernels
#define LP    40
#define EP    68   // epilogue scratch pitch in floats

typedef __attribute__((ext_vector_type(8))) short bf8;
typedef __attribute__((ext_vector_type(4))) float f4;

__device__ __forceinline__ float fast_rcp(float x) { return __builtin_amdgcn_rcpf(x); }
__device__ __forceinline__ float sigf(float x)   { return fast_rcp(1.f + __expf(-x)); }
__device__ __forceinline__ float tanh_f(float x) { return 1.f - 2.f * fast_rcp(1.f + __expf(2.f * x)); }

__device__ __forceinline__ float bf2f(unsigned short u) {
    return __uint_as_float(((unsigned)u) << 16);
}
__device__ __forceinline__ unsigned short f2bf(float f) {
    unsigned u = __float_as_uint(f);
    unsigned r = (u + 0x7fffu + ((u >> 16) & 1u)) >> 16;   // RNE
    return (unsigned short)r;
}
__device__ __forceinline__ unsigned pack2(float a, float b) {
    return (unsigned)f2bf(a) | ((unsigned)f2bf(b) << 16);
}

// async global->LDS, 16B per lane; LDS dest = wave-uniform base + lane*16
#define GLDS(gp, lp) __builtin_amdgcn_global_load_lds( \
    (const __attribute__((address_space(1))) void*)(gp), \
    (__attribute__((address_space(3))) void*)(lp), 16, 0, 0)

// ===========================================================================
// glk MFMA pass: acc[4][4] += A[128,KLEN]@B[128,KLEN]^T, bf16, rows dense.
// LDS tiles unpadded [128][32] bf16; XOR chunk swizzle so both the
// lane-contiguous staging and the b128 fragment reads are ~2-way (free).
// a0/b0: per-lane source ptrs (row = wave*32 + lane/4, chunk jl) at k=0.
// ===========================================================================
template<int KLEN, int LDB>
__device__ __forceinline__ void pass_glk(
    const unsigned short* __restrict__ a0,
    const unsigned short* __restrict__ b0,
    unsigned short* Asm, unsigned short* Bsm,
    unsigned short* la0, unsigned short* lb0,
    f4 (&acc)[4][4], int wm, int wn, int jq, int fr)
{
    const unsigned short* a1 = a0 + 16 * DM;
    const unsigned short* b1 = b0 + 16 * LDB;
#pragma unroll
    for (int k0 = 0; k0 < KLEN; k0 += 32) {
        __syncthreads();
        GLDS(a0 + k0, la0);
        GLDS(a1 + k0, la0 + 512);
        GLDS(b0 + k0, lb0);
        GLDS(b1 + k0, lb0 + 512);
        __syncthreads();   // compiler drains vmcnt before s_barrier
        bf8 af[4], bb[4];
#pragma unroll
        for (int i = 0; i < 4; ++i)
            af[i] = *(const bf8*)(Asm + (wm + i * 16 + fr) * 32 + jq);
#pragma unroll
        for (int j = 0; j < 4; ++j)
            bb[j] = *(const bf8*)(Bsm + (wn + j * 16 + fr) * 32 + jq);
#pragma unroll
        for (int i = 0; i < 4; ++i)
#pragma unroll
            for (int j = 0; j < 4; ++j)
                acc[i][j] = __builtin_amdgcn_mfma_f32_16x16x32_bf16(
                    af[i], bb[j], acc[i][j], 0, 0, 0);
    }
}

// ===========================================================================
// Legacy padded-LDS passes (post-round one-shot kernels; proven correct)
// ===========================================================================
template<int KLEN>
__device__ __forceinline__ void pass_bf(
    const unsigned short* __restrict__ aRow,
    const unsigned short* __restrict__ bRow,
    unsigned short* Asm, unsigned short* Bsm, f4 (&acc)[4][4])
{
    const int tid  = threadIdx.x;
    const int kh   = (tid & 1) * 16;
    const int srow = tid >> 1;
    const int lane = tid & 63, wave = tid >> 6;
    const int wm = (wave >> 1) * 64, wn = (wave & 1) * 64;
    const int fr = lane & 15, fk = (lane >> 4) * 8;
    unsigned short* da = Asm + srow * LP + kh;
    unsigned short* db = Bsm + srow * LP + kh;

    for (int k0 = 0; k0 < KLEN; k0 += 32) {
        __syncthreads();
        *(int4*)(da)     = *(const int4*)(aRow + k0 + kh);
        *(int4*)(da + 8) = *(const int4*)(aRow + k0 + kh + 8);
        *(int4*)(db)     = *(const int4*)(bRow + k0 + kh);
        *(int4*)(db + 8) = *(const int4*)(bRow + k0 + kh + 8);
        __syncthreads();
        bf8 af[4], bb[4];
#pragma unroll
        for (int i = 0; i < 4; ++i)
            af[i] = *(const bf8*)(Asm + (wm + i * 16 + fr) * LP + fk);
#pragma unroll
        for (int j = 0; j < 4; ++j)
            bb[j] = *(const bf8*)(Bsm + (wn + j * 16 + fr) * LP + fk);
#pragma unroll
        for (int i = 0; i < 4; ++i)
#pragma unroll
            for (int j = 0; j < 4; ++j)
                acc[i][j] = __builtin_amdgcn_mfma_f32_16x16x32_bf16(
                    af[i], bb[j], acc[i][j], 0, 0, 0);
    }
}

template<int KLEN>
__device__ __forceinline__ void pass_f32(
    const float* __restrict__ aRow,
    const unsigned short* __restrict__ bRow,
    unsigned short* Asm, unsigned short* Bsm, f4 (&acc)[4][4])
{
    const int tid  = threadIdx.x;
    const int kh   = (tid & 1) * 16;
    const int srow = tid >> 1;
    const int lane = tid & 63, wave = tid >> 6;
    const int wm = (wave >> 1) * 64, wn = (wave & 1) * 64;
    const int fr = lane & 15, fk = (lane >> 4) * 8;
    unsigned short* da = Asm + srow * LP + kh;
    unsigned short* db = Bsm + srow * LP + kh;

    for (int k0 = 0; k0 < KLEN; k0 += 32) {
        __syncthreads();
        {
            const float* s = aRow + k0 + kh;
            float4 v0 = *(const float4*)(s);
            float4 v1 = *(const float4*)(s + 4);
            float4 v2 = *(const float4*)(s + 8);
            float4 v3 = *(const float4*)(s + 12);
            *(int4*)(da)     = make_int4(pack2(v0.x, v0.y), pack2(v0.z, v0.w),
                                         pack2(v1.x, v1.y), pack2(v1.z, v1.w));
            *(int4*)(da + 8) = make_int4(pack2(v2.x, v2.y), pack2(v2.z, v2.w),
                                         pack2(v3.x, v3.y), pack2(v3.z, v3.w));
        }
        *(int4*)(db)     = *(const int4*)(bRow + k0 + kh);
        *(int4*)(db + 8) = *(const int4*)(bRow + k0 + kh + 8);
        __syncthreads();
        bf8 af[4], bb[4];
#pragma unroll
        for (int i = 0; i < 4; ++i)
            af[i] = *(const bf8*)(Asm + (wm + i * 16 + fr) * LP + fk);
#pragma unroll
        for (int j = 0; j < 4; ++j)
            bb[j] = *(const bf8*)(Bsm + (wn + j * 16 + fr) * LP + fk);
#pragma unroll
        for (int i = 0; i < 4; ++i)
#pragma unroll
            for (int j = 0; j < 4; ++j)
                acc[i][j] = __builtin_amdgcn_mfma_f32_16x16x32_bf16(
                    af[i], bb[j], acc[i][j], 0, 0, 0);
    }
}

// --------------------------- setup kernels ----------------------------------

__global__ __launch_bounds__(256) void k_lastidx(
    const int* __restrict__ indice, int* __restrict__ last_idx)
{
    const int n = blockIdx.x * 256 + threadIdx.x;
    if (n >= N_SEQ) return;
    int len = 0;
#pragma unroll
    for (int k = 0; k < KCH; ++k) len += (indice[n * KCH + k] != -1);
    last_idx[n] = indice[n * KCH + (len - 1)];
}

__global__ __launch_bounds__(1024) void k_hh0_bsum2(
    const float* __restrict__ bih, const float* __restrict__ bhh,
    const float* __restrict__ h0, const float* __restrict__ Whh,
    float* __restrict__ bsum2)
{
    const int jz = blockIdx.x, j = jz + 1;
    const int g = threadIdx.x;
    const int jd = j * 2 + 1;
    const float* wrow = Whh + ((size_t)jd * G4 + g) * DM;
    float s = bih[jd * G4 + g] + bhh[jd * G4 + g];
    for (int h = 0; h < DM; ++h) s = fmaf(h0[j * DM + h], wrow[h], s);
    const int c = (g & 255) * 4 + (g >> 8);
    bsum2[jz * G4 + c] = s;
}

__global__ __launch_bounds__(256) void k_init_states(
    const float* __restrict__ h0, const float* __restrict__ c0,
    unsigned short* __restrict__ hA, float* __restrict__ c_state)
{
    const int row = blockIdx.x;
    const int s = row >> 12;
    const int tree = (s < 4) ? s : 0;
    const int d = threadIdx.x;
    hA[(size_t)row * DM + d]      = f2bf(h0[tree * DM + d]);
    c_state[(size_t)row * DM + d] = c0[tree * DM + d];
}

__global__ __launch_bounds__(256) void k_zero4(float4* __restrict__ p)
{
    p[(size_t)blockIdx.x * 256 + threadIdx.x] = make_float4(0.f, 0.f, 0.f, 0.f);
}

__global__ __launch_bounds__(256) void k_prep_wcat(
    const float* __restrict__ Wih, const float* __restrict__ Whh,
    const float* __restrict__ bih, const float* __restrict__ bhh,
    unsigned short* __restrict__ wcat, float* __restrict__ bsumr)
{
    const int c = blockIdx.x, s = blockIdx.y;
    const int wsel = (s < 4) ? s * 2 : 1;
    const int d = c >> 2, g = c & 3;
    const size_t srcrow = ((size_t)wsel * G4 + g * DM + d) * DM;
    unsigned short* dst = wcat + ((size_t)s * G4 + c) * 512;
    const int t = threadIdx.x;
    dst[t]       = f2bf(Wih[srcrow + t]);
    dst[256 + t] = f2bf(Whh[srcrow + t]);
    if (t == 0)
        bsumr[s * G4 + c] = bih[wsel * G4 + g * DM + d] + bhh[wsel * G4 + g * DM + d];
}

__global__ __launch_bounds__(256) void k_prep_wcat2(
    const float* __restrict__ Wih, unsigned short* __restrict__ wcat2)
{
    const int c = blockIdx.x, jz = blockIdx.y, j = jz + 1;
    const int d = c >> 2, g = c & 3;
    const size_t srcrow = ((size_t)(j * 2 + 1) * G4 + g * DM + d) * DM;
    wcat2[((size_t)jz * G4 + c) * 256 + threadIdx.x] = f2bf(Wih[srcrow + threadIdx.x]);
}

__global__ __launch_bounds__(256) void k_prep_fcb(
    const float* __restrict__ fc, unsigned short* __restrict__ fcb)
{
    const int dout = blockIdx.x, z = blockIdx.y, t = threadIdx.x;
    fcb[((size_t)z * DM + dout) * DM + t] = f2bf(fc[(size_t)dout * 512 + z * DM + t]);
}

__global__ __launch_bounds__(256) void k_prep_fcb2(
    const float* __restrict__ fc, unsigned short* __restrict__ fcb2)
{
    const int dout = blockIdx.x, jz = blockIdx.y, j = jz + 1, t = threadIdx.x;
    const float* src = fc + ((size_t)j * DM + dout) * 512;
    unsigned short* dst = fcb2 + ((size_t)jz * DM + dout) * 512;
    dst[t]       = f2bf(src[t]);
    dst[t + 256] = f2bf(src[t + 256]);
}

__global__ __launch_bounds__(256) void k_prep_wwb(
    const float* __restrict__ W_w, unsigned short* __restrict__ wwb)
{
    const size_t i = (size_t)blockIdx.x * 256 + threadIdx.x;
    wwb[i] = f2bf(W_w[i]);
}

__device__ __forceinline__ void gather_slice(
    const float* __restrict__ h_tensor, const int* __restrict__ indice,
    unsigned short* __restrict__ xbuf, int zz, int kk, int blk)
{
    const int row = blk * 64 + (threadIdx.x >> 2);
    const int cb  = (threadIdx.x & 3) * 64;
    int idx = indice[row * KCH + kk]; if (idx < 0) idx = 0;
    const float* src = h_tensor + (size_t)idx * DM + cb;
    unsigned short* dst = xbuf + ((size_t)zz * N_SEQ + row) * DM + cb;
#pragma unroll
    for (int c = 0; c < 64; c += 4) {
        float4 v = *(const float4*)(src + c);
        *(uint2*)(dst + c) = make_uint2(pack2(v.x, v.y), pack2(v.z, v.w));
    }
}

__global__ __launch_bounds__(256) void k_gather_x0(
    const float* __restrict__ h_tensor, const int* __restrict__ indice,
    unsigned short* __restrict__ xbuf)
{
    const int slice = blockIdx.x >> 6, blk = blockIdx.x & 63;
    gather_slice(h_tensor, indice, xbuf, slice, slice ? (KCH - 1) : 0, blk);
}

// --------------------------- merged scan round ------------------------------
// grid (8, 32, 6):
//   bz<5 : scan for stream s=bz (XCD-swizzled: bn=by&7, bm=(by>>3)*8+bx so all
//          8 bn-siblings of one (bm,s) share id%8 -> same XCD -> A L2-local)
//   bz=5 : id5<128 -> acc_fc for round r-1 (y ping-pong);
//          id5>=128 -> gather xbuf slices for round r+1 (x ping-pong)
__global__ __launch_bounds__(256) void k_scan_merged(
    const unsigned short* __restrict__ xb_cur, unsigned short* __restrict__ xb_nxt,
    const unsigned short* __restrict__ yb_prev, unsigned short* __restrict__ yb_cur,
    const int* __restrict__ indice, const float* __restrict__ h_tensor,
    const unsigned short* __restrict__ h_in, unsigned short* __restrict__ h_out,
    float* __restrict__ c_state,
    const unsigned short* __restrict__ wcat, const float* __restrict__ bsumr,
    const unsigned short* __restrict__ fcb, unsigned short* __restrict__ ys0,
    int r)
{
    __shared__ __align__(16) unsigned short SMEM[8704];   // 17,408 B
    unsigned short* Asm = SMEM;
    unsigned short* Bsm = SMEM + 4096;

    const int tid  = threadIdx.x;
    const int lane = tid & 63, wave = tid >> 6;
    const int wm = (wave >> 1) * 64, wn = (wave & 1) * 64;
    const int fr = lane & 15;
    const int jq = ((lane >> 4) ^ ((fr >> 1) & 3)) * 8;        // frag-read swizzle
    const int lr = wave * 32 + (lane >> 2);                    // staging row
    const int jl = ((lane & 3) ^ ((lane >> 3) & 3)) * 8;       // staging swizzle
    unsigned short* la0 = Asm + wave * 1024;
    unsigned short* lb0 = Bsm + wave * 1024;

    const int bz = blockIdx.z;

    if (bz == 5) {
        const int id5 = blockIdx.x + 8 * blockIdx.y;
        if (id5 >= 128) {                 // gather role: xbuf for round r+1
            const int rr = r + 1;
            if (rr >= KCH) return;
            const int g = id5 - 128;
            const int zz = g >> 6;
            gather_slice(h_tensor, indice, xb_nxt, zz,
                         zz ? (KCH - 1 - rr) : rr, g & 63);
            return;
        }
        if (r == 0) return;               // acc role: fc-accumulate round r-1
        const int rp = r - 1;
        const int z = id5 >> 6;
        const int kslice = z ? (KCH - 1 - rp) : rp;
        const int row0 = (id5 & 31) * 128;
        const int c0 = ((id5 >> 5) & 1) * 128;

        const unsigned short* ay0 = yb_prev + ((size_t)z * N_SEQ + row0 + lr) * DM + jl;
        const unsigned short* bf0 = fcb + ((size_t)z * DM + c0 + lr) * DM + jl;

        f4 acc[4][4];
#pragma unroll
        for (int i = 0; i < 4; ++i)
#pragma unroll
            for (int j = 0; j < 4; ++j) acc[i][j] = (f4)(0.f);
        pass_glk<256, 256>(ay0, bf0, Asm, Bsm, la0, lb0, acc, wm, wn, jq, fr);

#pragma unroll
        for (int i = 0; i < 4; ++i)
#pragma unroll
            for (int j = 0; j < 4; ++j) {
                const int col = c0 + wn + j * 16 + fr;
#pragma unroll
                for (int reg = 0; reg < 4; ++reg) {
                    const int rowg = row0 + wm + i * 16 + (lane >> 4) * 4 + reg;
                    const size_t ix = ((size_t)rowg * KCH + kslice) * DM + col;
                    ys0[ix] = f2bf(bf2f(ys0[ix]) + acc[i][j][reg]);
                }
            }
        return;
    }

    // ---- scan role ----
    const int s = bz;
    const int k = (s < 4) ? r : (KCH - 1 - r);
    const int z = (s < 4) ? 0 : 1;
    const int bn = blockIdx.y & 7;
    const int bm = (blockIdx.y >> 3) * 8 + blockIdx.x;
    const int row0 = bm * 128, c0 = bn * 128;

    const unsigned short* xz = xb_cur + (size_t)z * N_SEQ * DM;
    const unsigned short* hs_in = h_in + (size_t)s * N_SEQ * DM;
    const unsigned short* ax0 = xz + (size_t)(row0 + lr) * DM + jl;
    const unsigned short* ah0 = hs_in + (size_t)(row0 + lr) * DM + jl;
    const unsigned short* bw0 = wcat + ((size_t)s * G4 + c0 + lr) * 512 + jl;

    f4 acc[4][4];
#pragma unroll
    for (int i = 0; i < 4; ++i)
#pragma unroll
        for (int j = 0; j < 4; ++j) acc[i][j] = (f4)(0.f);

    pass_glk<256, 512>(ax0, bw0, Asm, Bsm, la0, lb0, acc, wm, wn, jq, fr);
    pass_glk<256, 512>(ah0, bw0 + 256, Asm, Bsm, la0, lb0, acc, wm, wn, jq, fr);

    // ---- fused LSTM epilogue (round-5 proven) ----
    float* sc = (float*)SMEM + wave * (16 * EP);
    __syncthreads();
#pragma unroll
    for (int i = 0; i < 4; ++i) {
#pragma unroll
        for (int j = 0; j < 4; ++j) {
            const int colL = j * 16 + fr;
            const int rbase = (lane >> 4) * 4;
#pragma unroll
            for (int reg = 0; reg < 4; ++reg)
                sc[(rbase + reg) * EP + colL] = acc[i][j][reg];
        }
        __syncthreads();
        const int rowg = row0 + wm + i * 16 + fr;
        const bool m = (indice[rowg * KCH + k] != -1);
#pragma unroll
        for (int q = 0; q < 4; ++q) {
            const int dL = (lane >> 4) + q * 4;
            const f4 gv = *(const f4*)(sc + fr * EP + dL * 4);
            const f4 bb = *(const f4*)(bsumr + s * G4 + c0 + wn + dL * 4);
            const int d = ((c0 + wn) >> 2) + dL;
            const float ii = sigf(gv.x + bb.x);
            const float ff = sigf(gv.y + bb.y);
            const float uu = tanh_f(gv.z + bb.z);
            const float oo = sigf(gv.w + bb.w);
            const size_t cix = ((size_t)s * N_SEQ + rowg) * DM + d;
            const float c_old = c_state[cix];
            const float cn = ff * c_old + ii * uu;
            const float cw = m ? cn : c_old;
            c_state[cix] = cw;
            const float hn = oo * tanh_f(cn);
            const unsigned short hv = m ? f2bf(hn) : hs_in[(size_t)rowg * DM + d];
            h_out[cix] = hv;
            if (s == 0)
                yb_cur[(size_t)rowg * DM + d] = m ? f2bf(hn) : (unsigned short)0;
            else if (s == 4)
                yb_cur[(size_t)(N_SEQ + rowg) * DM + d] = m ? f2bf(hn) : (unsigned short)0;
        }
        __syncthreads();
    }
}

// tail: acc_fc for r=15.  grid (2, 32, 2)
__global__ __launch_bounds__(256) void k_acc_tail(
    const unsigned short* __restrict__ ybuf, const unsigned short* __restrict__ fcb,
    unsigned short* __restrict__ ys0)
{
    __shared__ __align__(16) unsigned short SMEM[8192];
    unsigned short* Asm = SMEM;
    unsigned short* Bsm = SMEM + 4096;
    const int tid = threadIdx.x;
    const int lane = tid & 63, wave = tid >> 6;
    const int wm = (wave >> 1) * 64, wn = (wave & 1) * 64;
    const int fr = lane & 15;
    const int jq = ((lane >> 4) ^ ((fr >> 1) & 3)) * 8;
    const int lr = wave * 32 + (lane >> 2);
    const int jl = ((lane & 3) ^ ((lane >> 3) & 3)) * 8;
    unsigned short* la0 = Asm + wave * 1024;
    unsigned short* lb0 = Bsm + wave * 1024;

    const int z = blockIdx.z;
    const int kslice = z ? 0 : (KCH - 1);
    const int row0 = blockIdx.y * 128, c0 = blockIdx.x * 128;

    const unsigned short* ay0 = ybuf + ((size_t)z * N_SEQ + row0 + lr) * DM + jl;
    const unsigned short* bf0 = fcb + ((size_t)z * DM + c0 + lr) * DM + jl;

    f4 acc[4][4];
#pragma unroll
    for (int i = 0; i < 4; ++i)
#pragma unroll
        for (int j = 0; j < 4; ++j) acc[i][j] = (f4)(0.f);
    pass_glk<256, 256>(ay0, bf0, Asm, Bsm, la0, lb0, acc, wm, wn, jq, fr);

#pragma unroll
    for (int i = 0; i < 4; ++i)
#pragma unroll
        for (int j = 0; j < 4; ++j) {
            const int col = c0 + wn + j * 16 + fr;
#pragma unroll
            for (int reg = 0; reg < 4; ++reg) {
                const int rowg = row0 + wm + i * 16 + (lane >> 4) * 4 + reg;
                const size_t ix = ((size_t)rowg * KCH + kslice) * DM + col;
                ys0[ix] = f2bf(bf2f(ys0[ix]) + acc[i][j][reg]);
            }
        }
}

// --------------------------- post-round kernels -----------------------------

__global__ __launch_bounds__(256) void k_bwd_mfma(
    const float* __restrict__ h_tensor, const int* __restrict__ last_idx,
    const unsigned short* __restrict__ wcat2, const float* __restrict__ bsum2,
    const float* __restrict__ c0, unsigned short* __restrict__ yb_last)
{
    __shared__ __align__(16) unsigned short SMEM[2 * 128 * LP];
    const int jz = blockIdx.z, j = jz + 1;
    const int row0 = blockIdx.y * 128, c0t = blockIdx.x * 128;
    const int tid = threadIdx.x;
    const int srow = tid >> 1;

    const float* aF = h_tensor + (size_t)last_idx[row0 + srow] * DM;
    const unsigned short* bR = wcat2 + ((size_t)jz * G4 + c0t + srow) * 256;

    f4 acc[4][4];
#pragma unroll
    for (int i = 0; i < 4; ++i)
#pragma unroll
        for (int jj = 0; jj < 4; ++jj) acc[i][jj] = (f4)(0.f);

    pass_f32<256>(aF, bR, SMEM, SMEM + 128 * LP, acc);

    const int lane = tid & 63, wave = tid >> 6;
    const int wm = (wave >> 1) * 64, wn = (wave & 1) * 64;
    float* sc = (float*)SMEM + wave * (16 * EP);

    __syncthreads();
#pragma unroll
    for (int i = 0; i < 4; ++i) {
#pragma unroll
        for (int jj = 0; jj < 4; ++jj) {
            const int colL = jj * 16 + (lane & 15);
            const int rbase = (lane >> 4) * 4;
#pragma unroll
            for (int reg = 0; reg < 4; ++reg)
                sc[(rbase + reg) * EP + colL] = acc[i][jj][reg];
        }
        __syncthreads();
        const int rowg = row0 + wm + i * 16 + (lane & 15);
#pragma unroll
        for (int q = 0; q < 4; ++q) {
            const int dL = (lane >> 4) + q * 4;
            const f4 gv = *(const f4*)(sc + (lane & 15) * EP + dL * 4);
            const f4 bb = *(const f4*)(bsum2 + jz * G4 + c0t + wn + dL * 4);
            const int d = ((c0t + wn) >> 2) + dL;
            const float ii = sigf(gv.x + bb.x);
            const float ff = sigf(gv.y + bb.y);
            const float uu = tanh_f(gv.z + bb.z);
            const float oo = sigf(gv.w + bb.w);
            const float cn = ff * c0[j * DM + d] + ii * uu;
            yb_last[((size_t)jz * N_SEQ + rowg) * DM + d] = f2bf(oo * tanh_f(cn));
        }
        __syncthreads();
    }
}

__global__ __launch_bounds__(256) void k_wx_mfma(
    const float* __restrict__ x, const unsigned short* __restrict__ wwb,
    const float* __restrict__ W_b, unsigned short* __restrict__ Wx)
{
    __shared__ __align__(16) unsigned short SMEM[2 * 128 * LP];
    const int row0 = blockIdx.y * 128, c0 = blockIdx.x * 128;
    const int tid = threadIdx.x;
    const int srow = tid >> 1;

    const float* aF = x + (size_t)(row0 + srow) * DM;
    const unsigned short* bR = wwb + (size_t)(c0 + srow) * DM;

    f4 acc[4][4];
#pragma unroll
    for (int i = 0; i < 4; ++i)
#pragma unroll
        for (int j = 0; j < 4; ++j) acc[i][j] = (f4)(0.f);

    pass_f32<256>(aF, bR, SMEM, SMEM + 128 * LP, acc);

    const int lane = tid & 63, wave = tid >> 6;
    const int wm = (wave >> 1) * 64, wn = (wave & 1) * 64;
#pragma unroll
    for (int i = 0; i < 4; ++i)
#pragma unroll
        for (int j = 0; j < 4; ++j) {
            const int col = c0 + wn + j * 16 + (lane & 15);
            const float bv = W_b[col];
#pragma unroll
            for (int reg = 0; reg < 4; ++reg) {
                const int rowg = row0 + wm + i * 16 + (lane >> 4) * 4 + reg;
                Wx[(size_t)rowg * G4 + col] = f2bf(acc[i][j][reg] + bv);
            }
        }
}

__global__ __launch_bounds__(256) void k_fc_last_mfma(
    const unsigned short* __restrict__ h_final, const unsigned short* __restrict__ yb_last,
    const unsigned short* __restrict__ fcb2, unsigned short* __restrict__ ys_last)
{
    __shared__ __align__(16) unsigned short SMEM[2 * 128 * LP];
    const int jz = blockIdx.z;
    const int row0 = blockIdx.y * 128, c0 = blockIdx.x * 128;
    const int tid = threadIdx.x;
    const int srow = tid >> 1;

    const unsigned short* aH1 = h_final + ((size_t)(1 + jz) * N_SEQ + row0 + srow) * DM;
    const unsigned short* aH2 = yb_last + ((size_t)jz * N_SEQ + row0 + srow) * DM;
    const unsigned short* bR  = fcb2 + ((size_t)jz * DM + c0 + srow) * 512;

    f4 acc[4][4];
#pragma unroll
    for (int i = 0; i < 4; ++i)
#pragma unroll
        for (int j = 0; j < 4; ++j) acc[i][j] = (f4)(0.f);

    pass_bf<256>(aH1, bR, SMEM, SMEM + 128 * LP, acc);
    pass_bf<256>(aH2, bR + 256, SMEM, SMEM + 128 * LP, acc);

    const int lane = tid & 63, wave = tid >> 6;
    const int wm = (wave >> 1) * 64, wn = (wave & 1) * 64;
#pragma unroll
    for (int i = 0; i < 4; ++i)
#pragma unroll
        for (int j = 0; j < 4; ++j) {
            const int col = c0 + wn + j * 16 + (lane & 15);
#pragma unroll
            for (int reg = 0; reg < 4; ++reg) {
                const int rowg = row0 + wm + i * 16 + (lane >> 4) * 4 + reg;
                ys_last[((size_t)jz * N_SEQ + rowg) * DM + col] = f2bf(acc[i][j][reg]);
            }
        }
}

__global__ __launch_bounds__(256) void k_final(
    const unsigned short* __restrict__ Wx, const unsigned short* __restrict__ ys0,
    const unsigned short* __restrict__ ys_last, const float* __restrict__ c_tensor,
    const int* __restrict__ indice, float* __restrict__ out)
{
    const int n = blockIdx.x, d = threadIdx.x;
    const float Wf = bf2f(Wx[(size_t)n * G4 + d]);
    const float Wi = bf2f(Wx[(size_t)n * G4 + DM + d]);
    const float Wu = bf2f(Wx[(size_t)n * G4 + 2 * DM + d]);
    const float Wo = bf2f(Wx[(size_t)n * G4 + 3 * DM + d]);
    float bf = 0.f;
#pragma unroll
    for (int k = 0; k < KCH; ++k) {
        const int id = indice[n * KCH + k];
        if (id >= 0)
            bf += sigf(Wf + bf2f(ys0[((size_t)n * KCH + k) * DM + d])) *
                  c_tensor[(size_t)id * DM + d];
    }
    const float bi = sigf(bf2f(ys_last[((size_t)0 * N_SEQ + n) * DM + d]) + Wi);
    const float bu = tanh_f(bf2f(ys_last[((size_t)1 * N_SEQ + n) * DM + d]) + Wu);
    const float bo = sigf(bf2f(ys_last[((size_t)2 * N_SEQ + n) * DM + d]) + Wo);
    const float nc = bi * bu + bf;
    const float nh = bo * tanh_f(nc);
    out[(size_t)n * DM + d] = nh;
    out[(size_t)N_SEQ * DM + (size_t)n * DM + d] = nc;
}

// --------------------------- launcher ---------------------------------------
extern "C" void kernel_launch(void* const* d_in, const int* in_sizes, int n_in,
                              void* d_out, int out_size, void* d_ws, size_t ws_size,
                              hipStream_t stream)
{
    const float* x        = (const float*)d_in[0];
    const float* h_tensor = (const float*)d_in[1];
    const float* c_tensor = (const float*)d_in[2];
    const int*   indice   = (const int*)d_in[3];
    const float* W_w      = (const float*)d_in[4];
    const float* W_b      = (const float*)d_in[5];
    const float* h0       = (const float*)d_in[6];
    const float* c0       = (const float*)d_in[7];
    const float* Wih      = (const float*)d_in[8];
    const float* Whh      = (const float*)d_in[9];
    const float* bih      = (const float*)d_in[10];
    const float* bhh      = (const float*)d_in[11];
    const float* fc       = (const float*)d_in[12];
    float* out = (float*)d_out;

    // ---- workspace layout; need = 97,816,576 B (< proven 100,728,832) ----
    char* base = (char*)d_ws;
    float*          c_state  = (float*)(base + 0);                   // 20,971,520
    int*            last_idx = (int*)  (base + 20971520);            //     16,384
    float*          bsumr    = (float*)(base + 20987904);            //     20,480
    unsigned short* hA       = (unsigned short*)(base + 21008384);   // 10,485,760
    unsigned short* hB       = (unsigned short*)(base + 31494144);   // 10,485,760
    unsigned short* ys0      = (unsigned short*)(base + 41979904);   // 33,554,432
    unsigned short* ybufA    = (unsigned short*)(base + 75534336);   //  4,194,304
    unsigned short* ybufB    = (unsigned short*)(base + 79728640);   //  4,194,304
    unsigned short* xbufA    = (unsigned short*)(base + 83922944);   //  4,194,304
    unsigned short* fcb      = (unsigned short*)(base + 88117248);   //    262,144
    unsigned short* postbuf  = (unsigned short*)(base + 88379392);   //  4,194,304
    unsigned short* wcat     = (unsigned short*)(base + 92573696);   //  5,242,880
    const size_t need = 97816576;
    if (ws_size < need) return;   // diagnostic: zero-output absmax fail

    // aliases (disjoint lifetimes):
    unsigned short* xbufB   = postbuf;               // rounds only
    unsigned short* wcat2   = postbuf;               // post (1,572,864 B)
    unsigned short* fcb2    = postbuf + 786432;      // post (786,432 B)
    unsigned short* wwb     = postbuf + 1179648;     // post (524,288 B)
    float*          bsum2   = (float*)(postbuf + 1441792);  // post (12,288 B)
    unsigned short* yb_last = ybufA;                 // post (6.29 MB spans ybufA+B)
    unsigned short* ys_last = hB;                    // post (final h in hA)
    unsigned short* WxBuf   = hA;                    // post-fc_last (hA dead)

    k_lastidx<<<16, 256, 0, stream>>>(indice, last_idx);
    k_init_states<<<5 * N_SEQ, 256, 0, stream>>>(h0, c0, hA, c_state);
    k_zero4<<<8192, 256, 0, stream>>>((float4*)ys0);
    k_prep_wcat<<<dim3(G4, 5), 256, 0, stream>>>(Wih, Whh, bih, bhh, wcat, bsumr);
    k_prep_fcb<<<dim3(DM, 2), 256, 0, stream>>>(fc, fcb);
    k_gather_x0<<<128, 256, 0, stream>>>(h_tensor, indice, xbufA);

    for (int r = 0; r < KCH; ++r) {
        const unsigned short* xb_cur = (r & 1) ? xbufB : xbufA;
        unsigned short* xb_nxt       = (r & 1) ? xbufA : xbufB;
        const unsigned short* yb_prev = (r & 1) ? ybufA : ybufB;
        unsigned short* yb_cur        = (r & 1) ? ybufB : ybufA;
        const unsigned short* h_in = (r & 1) ? hB : hA;
        unsigned short* h_out      = (r & 1) ? hA : hB;
        k_scan_merged<<<dim3(8, 32, 6), 256, 0, stream>>>(
            xb_cur, xb_nxt, yb_prev, yb_cur, indice, h_tensor,
            h_in, h_out, c_state, wcat, bsumr, fcb, ys0, r);
    }
    // r=15 odd -> final h in hA; y_cur(r=15) in ybufB.

    k_acc_tail<<<dim3(2, 32, 2), 256, 0, stream>>>(ybufB, fcb, ys0);

    // post preps into postbuf (xbufB dead)
    k_prep_wcat2<<<dim3(G4, 3), 256, 0, stream>>>(Wih, wcat2);
    k_hh0_bsum2<<<3, 1024, 0, stream>>>(bih, bhh, h0, Whh, bsum2);
    k_prep_fcb2<<<dim3(DM, 3), 256, 0, stream>>>(fc, fcb2);
    k_prep_wwb<<<1024, 256, 0, stream>>>(W_w, wwb);

    k_bwd_mfma<<<dim3(8, 32, 3), 256, 0, stream>>>(
        h_tensor, last_idx, wcat2, bsum2, c0, yb_last);
    k_fc_last_mfma<<<dim3(2, 32, 3), 256, 0, stream>>>(hA, yb_last, fcb2, ys_last);
    k_wx_mfma<<<dim3(8, 32), 256, 0, stream>>>(x, wwb, W_b, WxBuf);

    k_final<<<N_SEQ, 256, 0, stream>>>(WxBuf, ys0, ys_last, c_tensor, indice, out);
}